// Round 11
// baseline (1634.153 us; speedup 1.0000x reference)
//
#include <hip/hip_runtime.h>

typedef unsigned short u16;
typedef __attribute__((ext_vector_type(4))) float f32x4;
typedef __attribute__((ext_vector_type(8))) __bf16 bf16x8;
typedef __attribute__((ext_vector_type(4))) unsigned short u16x4;

static __device__ __forceinline__ u16 f2bf(float f) {
  union { float f; unsigned u; } v; v.f = f;
  unsigned r = v.u + 0x7fffu + ((v.u >> 16) & 1u);
  return (u16)(r >> 16);
}
static __device__ __forceinline__ float bf2f(u16 u) {
  union { unsigned u; float f; } x; x.u = ((unsigned)u) << 16; return x.f;
}

#define GLD_LDS(g, l) __builtin_amdgcn_global_load_lds( \
    (const __attribute__((address_space(1))) void*)(g), \
    (__attribute__((address_space(3))) void*)(l), 16, 0, 0)

// ---------------------------------------------------------------------------
// gemm2b: 256x256-tile BK=32 8-wave GEMM, 64 KB LDS -> 2 blocks/CU.
// R5's exact two-quadrant schedule; T2 swizzle f(row)=(row>>1)&3 (R7-verified,
// 0 conflicts); counted vmcnt(4); setprio. Cross-block co-residency hides
// epilogue + barrier stalls that R5's 1-block/CU config exposed.
// EPI: 0 = Cf = alpha*acc + bias; 2 = Cb = bf16(acc+bias); 3 = bf16 relu.
// ---------------------------------------------------------------------------
template<int EPI>
__global__ __launch_bounds__(512, 2)
void gemm2b(const u16* __restrict__ A, const u16* __restrict__ B,
            float* __restrict__ Cf, u16* __restrict__ Cb,
            const float* __restrict__ bias, float alpha,
            int K, int lda, int ldb, int ldc, int mtiles, int gm, int nsplit,
            long long sA, long long sB, long long sC)
{
  __shared__ u16 lds[32768];  // 64KB: A[buf] at buf*8192, B at 16384+buf*8192
  const int t = threadIdx.x;
  const int w = t >> 6, l = t & 63;
  const int l15 = l & 15, l16 = l >> 4;
  const int wr = w >> 2, wc = w & 3;

  int wg = blockIdx.x;
  const int nwg = gridDim.x;
  {
    const int q = nwg >> 3, r = nwg & 7;
    const int xcd = wg & 7, loc = wg >> 3;
    wg = (xcd < r ? xcd * (q + 1) : r * (q + 1) + (xcd - r) * q) + loc;
  }
  const int ntiles = nwg / mtiles;
  const int gsz = gm * ntiles;
  const int gi = wg / gsz;
  const int rr = wg - gi * gsz;
  const int nt = rr / gm;
  const int mt = gi * gm + (rr - nt * gm);
  const int m0 = mt << 8, n0 = nt << 8;

  const int bz = blockIdx.z;
  int batch = bz, sp = 0;
  if (nsplit > 1) { batch = bz / nsplit; sp = bz - batch * nsplit; }
  const u16* Ab = A + (long long)batch * sA + (long long)sp * K;
  const u16* Bb = B + (long long)batch * sB + (long long)sp * K;
  const long long cbase = (long long)bz * sC;

  // staging: unit u = j*512 + w*64 + l -> row u>>2 (64B rows), dest slot u&3,
  // src slot (u&3)^((row>>1)&3) (pre-swizzled global; linear gload_lds dest).
  int srow[2], ssrc[2], sdst[2];
#pragma unroll
  for (int j = 0; j < 2; ++j) {
    const int u = (j << 9) + (w << 6) + l;
    srow[j] = u >> 2;
    ssrc[j] = (((u & 3) ^ ((srow[j] >> 1) & 3)) << 3);
    sdst[j] = ((j << 9) + (w << 6)) << 3;   // wave-uniform elem offset
  }
  auto STAGE = [&](int buf, int kt) {
#pragma unroll
    for (int j = 0; j < 2; ++j)
      GLD_LDS(Ab + (long long)(m0 + srow[j]) * lda + kt * 32 + ssrc[j],
              &lds[buf * 8192 + sdst[j]]);
#pragma unroll
    for (int j = 0; j < 2; ++j)
      GLD_LDS(Bb + (long long)(n0 + srow[j]) * ldb + kt * 32 + ssrc[j],
              &lds[16384 + buf * 8192 + sdst[j]]);
  };

  const int nkt = K >> 5;
  STAGE(0, 0);
  if (nkt > 1) STAGE(1, 1);

  f32x4 acc[8][4] = {};
  const int aRow = wr * 128 + l15;
  const int bRow = wc * 64 + l15;

  for (int kt = 0; kt < nkt; ++kt) {
    const int buf = kt & 1;
    if (kt < nkt - 1) asm volatile("s_waitcnt vmcnt(4)" ::: "memory");
    else              asm volatile("s_waitcnt vmcnt(0)" ::: "memory");
    __builtin_amdgcn_s_barrier();
    __builtin_amdgcn_sched_barrier(0);

    const int abase = buf * 8192;
    const int bbase = 16384 + buf * 8192;
    bf16x8 af[4], bg[4];
#pragma unroll
    for (int mf = 0; mf < 4; ++mf) {
      const int r2 = aRow + mf * 16;
      af[mf] = *(const bf16x8*)&lds[abase + r2 * 32 + ((l16 ^ ((r2 >> 1) & 3)) << 3)];
    }
#pragma unroll
    for (int nf = 0; nf < 4; ++nf) {
      const int r2 = bRow + nf * 16;
      bg[nf] = *(const bf16x8*)&lds[bbase + r2 * 32 + ((l16 ^ ((r2 >> 1) & 3)) << 3)];
    }

    __builtin_amdgcn_s_setprio(1);
#pragma unroll
    for (int mf = 0; mf < 4; ++mf)
#pragma unroll
      for (int nf = 0; nf < 4; ++nf)
        acc[mf][nf] = __builtin_amdgcn_mfma_f32_16x16x32_bf16(af[mf], bg[nf], acc[mf][nf], 0, 0, 0);
    __builtin_amdgcn_s_setprio(0);

    bf16x8 ah[4];
#pragma unroll
    for (int mf = 0; mf < 4; ++mf) {
      const int r2 = aRow + 64 + mf * 16;
      ah[mf] = *(const bf16x8*)&lds[abase + r2 * 32 + ((l16 ^ ((r2 >> 1) & 3)) << 3)];
    }

    asm volatile("s_waitcnt lgkmcnt(0)" ::: "memory");
    __builtin_amdgcn_s_barrier();
    __builtin_amdgcn_sched_barrier(0);
    if (kt + 2 < nkt) STAGE(buf, kt + 2);

    __builtin_amdgcn_s_setprio(1);
#pragma unroll
    for (int mf = 0; mf < 4; ++mf)
#pragma unroll
      for (int nf = 0; nf < 4; ++nf)
        acc[mf + 4][nf] = __builtin_amdgcn_mfma_f32_16x16x32_bf16(ah[mf], bg[nf], acc[mf + 4][nf], 0, 0, 0);
    __builtin_amdgcn_s_setprio(0);
  }

#pragma unroll
  for (int mf = 0; mf < 8; ++mf) {
    const int rbase = m0 + wr * 128 + mf * 16 + l16 * 4;
#pragma unroll
    for (int nf = 0; nf < 4; ++nf) {
      const int col = n0 + wc * 64 + nf * 16 + l15;
      const float bv = bias ? bias[col] : 0.f;
#pragma unroll
      for (int r = 0; r < 4; ++r) {
        const long long idx = cbase + (long long)(rbase + r) * ldc + col;
        const float v = acc[mf][nf][r];
        if (EPI == 0)      Cf[idx] = alpha * v + bv;
        else if (EPI == 2) Cb[idx] = f2bf(v + bv);
        else               { float x = v + bv; Cb[idx] = f2bf(x > 0.f ? x : 0.f); }
      }
    }
  }
}

// ---- legacy 128x128 engine (small shapes: QKV) ----
template<int EPI>
__global__ __launch_bounds__(256)
void gemm_bt(const u16* __restrict__ A, const u16* __restrict__ B,
             float* __restrict__ Cf, u16* __restrict__ Cb,
             const float* __restrict__ bias, float alpha,
             int K, int lda, int ldb, int ldc, int mtiles, int gm, int nsplit,
             long long sA, long long sB, long long sC)
{
  __shared__ u16 ldsA[128 * 32];
  __shared__ u16 ldsB[128 * 32];
  const int t = threadIdx.x;
  const int w = t >> 6, l = t & 63;

  int wg = blockIdx.x;
  const int nwg = gridDim.x;
  {
    const int q = nwg >> 3, r = nwg & 7;
    const int xcd = wg & 7, loc = wg >> 3;
    wg = (xcd < r ? xcd * (q + 1) : r * (q + 1) + (xcd - r) * q) + loc;
  }
  const int ntiles = nwg / mtiles;
  const int gsz = gm * ntiles;
  const int gi = wg / gsz;
  const int rr = wg - gi * gsz;
  const int nt = rr / gm;
  const int mt = gi * gm + (rr - nt * gm);
  const int m0 = mt << 7, n0 = nt << 7;

  const int bzRaw = blockIdx.z;
  int batch = bzRaw, sp = 0;
  if (nsplit > 1) { batch = bzRaw / nsplit; sp = bzRaw - batch * nsplit; }
  const u16* Ab = A + (long long)batch * sA + (long long)sp * K;
  const u16* Bb = B + (long long)batch * sB + (long long)sp * K;
  const long long cbase = (long long)bzRaw * sC;

  const int wr = (w >> 1) << 6, wc = (w & 1) << 6;
  const int l15 = l & 15, l16 = l >> 4;
  f32x4 acc[4][4] = {};

  for (int k0 = 0; k0 < K; k0 += 32) {
#pragma unroll
    for (int r = 0; r < 2; ++r) {
      const int o = (r << 12) + (t << 4);
      const int row = o >> 6;
      const int cole = (o & 63) >> 1;
      GLD_LDS(Ab + (long long)(m0 + row) * lda + k0 + cole, &ldsA[(r << 11) + (w << 9)]);
      GLD_LDS(Bb + (long long)(n0 + row) * ldb + k0 + cole, &ldsB[(r << 11) + (w << 9)]);
    }
    __syncthreads();
    bf16x8 af[4], bg[4];
#pragma unroll
    for (int i = 0; i < 4; ++i) {
      af[i] = *(const bf16x8*)&ldsA[(wr + i * 16 + l15) * 32 + l16 * 8];
      bg[i] = *(const bf16x8*)&ldsB[(wc + i * 16 + l15) * 32 + l16 * 8];
    }
#pragma unroll
    for (int i = 0; i < 4; ++i)
#pragma unroll
      for (int j = 0; j < 4; ++j)
        acc[i][j] = __builtin_amdgcn_mfma_f32_16x16x32_bf16(af[i], bg[j], acc[i][j], 0, 0, 0);
    __syncthreads();
  }

#pragma unroll
  for (int i = 0; i < 4; ++i) {
    const int rbase = m0 + wr + i * 16 + l16 * 4;
#pragma unroll
    for (int j = 0; j < 4; ++j) {
      const int col = n0 + wc + j * 16 + l15;
      const float bv = bias ? bias[col] : 0.f;
#pragma unroll
      for (int r = 0; r < 4; ++r) {
        const long long idx = cbase + (long long)(rbase + r) * ldc + col;
        const float v = acc[i][j][r];
        if (EPI == 0)      Cf[idx] = alpha * v + bv;
        else if (EPI == 1) Cf[idx] += v + bv;
        else if (EPI == 2) Cb[idx] = f2bf(v + bv);
        else               { float x = v + bv; Cb[idx] = f2bf(x > 0.f ? x : 0.f); }
      }
    }
  }
}

// ---------------- fused flash attention: 4 waves split-KV, in-LDS merge -----
__device__ __forceinline__ void fstep(
    const bf16x8 (&ck)[4][2], const bf16x8 (&cv)[4][2],
    bf16x8 (&nk)[4][2], bf16x8 (&nv)[4][2],
    const bf16x8 (&qf)[2], float (&m)[4], float (&ls)[4], f32x4 (&o)[4],
    const u16* qb, const u16* vb, int kvn, u16* pl, int l15, int l16)
{
  f32x4 s[4] = {};
#pragma unroll
  for (int ni = 0; ni < 4; ++ni)
#pragma unroll
    for (int kk = 0; kk < 2; ++kk)
      s[ni] = __builtin_amdgcn_mfma_f32_16x16x32_bf16(qf[kk], ck[ni][kk], s[ni], 0, 0, 0);
#pragma unroll
  for (int ni = 0; ni < 4; ++ni)
#pragma unroll
    for (int kk = 0; kk < 2; ++kk)
      nk[ni][kk] = *(const bf16x8*)(qb + (kvn + ni * 16 + l15) * 256 + 64 + kk * 32 + l16 * 8);
#pragma unroll
  for (int ni = 0; ni < 4; ++ni) s[ni] *= 0.125f;
  float al[4], ps[4];
#pragma unroll
  for (int r = 0; r < 4; ++r) {
    float v = fmaxf(fmaxf(s[0][r], s[1][r]), fmaxf(s[2][r], s[3][r]));
    v = fmaxf(v, __shfl_xor(v, 1)); v = fmaxf(v, __shfl_xor(v, 2));
    v = fmaxf(v, __shfl_xor(v, 4)); v = fmaxf(v, __shfl_xor(v, 8));
    const float mn = fmaxf(m[r], v);
    al[r] = __expf(m[r] - mn);
    m[r] = mn;
    ps[r] = 0.f;
  }
#pragma unroll
  for (int ni = 0; ni < 4; ++ni)
#pragma unroll
    for (int r = 0; r < 4; ++r) {
      const float p = __expf(s[ni][r] - m[r]);
      ps[r] += p;
      pl[(l16 * 4 + r) * 72 + ni * 16 + l15] = f2bf(p);
    }
#pragma unroll
  for (int r = 0; r < 4; ++r) {
    float t = ps[r];
    t += __shfl_xor(t, 1); t += __shfl_xor(t, 2);
    t += __shfl_xor(t, 4); t += __shfl_xor(t, 8);
    ls[r] = ls[r] * al[r] + t;
  }
#pragma unroll
  for (int nd = 0; nd < 4; ++nd)
#pragma unroll
    for (int r = 0; r < 4; ++r) o[nd][r] *= al[r];
  bf16x8 pa[2];
#pragma unroll
  for (int kk = 0; kk < 2; ++kk)
    pa[kk] = *(const bf16x8*)&pl[l15 * 72 + kk * 32 + l16 * 8];
#pragma unroll
  for (int nd = 0; nd < 4; ++nd)
#pragma unroll
    for (int kk = 0; kk < 2; ++kk)
      o[nd] = __builtin_amdgcn_mfma_f32_16x16x32_bf16(pa[kk], cv[nd][kk], o[nd], 0, 0, 0);
#pragma unroll
  for (int nd = 0; nd < 4; ++nd)
#pragma unroll
    for (int kk = 0; kk < 2; ++kk)
      nv[nd][kk] = *(const bf16x8*)(vb + (nd * 16 + l15) * 2048 + kvn + kk * 32 + l16 * 8);
}

__global__ __launch_bounds__(256)
void flash4_k(const u16* __restrict__ qkv, const u16* __restrict__ vT,
              u16* __restrict__ head)
{
  __shared__ u16 plbuf[4][16 * 72];
  __shared__ float poL[4][16][64];
  __shared__ float pmL[4][16], plsL[4][16];
  const int t = threadIdx.x, sp = t >> 6, l = t & 63;
  const int l15 = l & 15, l16 = l >> 4;
  const int b = blockIdx.x >> 7, q0 = (blockIdx.x & 127) << 4;
  const int kvb = sp << 9;
  const u16* qb = qkv + (long long)b * 2048 * 256;
  const u16* vb = vT + (long long)b * 64 * 2048;
  u16* pl = &plbuf[sp][0];
  bf16x8 qf[2];
#pragma unroll
  for (int kk = 0; kk < 2; ++kk)
    qf[kk] = *(const bf16x8*)(qb + (q0 + l15) * 256 + kk * 32 + l16 * 8);
  float m[4], ls[4];
  f32x4 o[4] = {};
#pragma unroll
  for (int r = 0; r < 4; ++r) { m[r] = -1e30f; ls[r] = 0.f; }
  bf16x8 ka[4][2], va[4][2], kb[4][2], vb2[4][2];
#pragma unroll
  for (int ni = 0; ni < 4; ++ni)
#pragma unroll
    for (int kk = 0; kk < 2; ++kk) {
      ka[ni][kk] = *(const bf16x8*)(qb + (kvb + ni * 16 + l15) * 256 + 64 + kk * 32 + l16 * 8);
      va[ni][kk] = *(const bf16x8*)(vb + (ni * 16 + l15) * 2048 + kvb + kk * 32 + l16 * 8);
    }
  for (int ti = 0; ti < 8; ti += 2) {
    const int n1 = kvb + (ti + 1 < 8 ? (ti + 1) * 64 : 7 * 64);
    const int n2 = kvb + (ti + 2 < 8 ? (ti + 2) * 64 : 7 * 64);
    fstep(ka, va, kb, vb2, qf, m, ls, o, qb, vb, n1, pl, l15, l16);
    fstep(kb, vb2, ka, va, qf, m, ls, o, qb, vb, n2, pl, l15, l16);
  }
#pragma unroll
  for (int nd = 0; nd < 4; ++nd)
#pragma unroll
    for (int r = 0; r < 4; ++r)
      poL[sp][l16 * 4 + r][nd * 16 + l15] = o[nd][r];
  if (l15 == 0) {
#pragma unroll
    for (int r = 0; r < 4; ++r) {
      pmL[sp][l16 * 4 + r] = m[r];
      plsL[sp][l16 * 4 + r] = ls[r];
    }
  }
  __syncthreads();
#pragma unroll
  for (int i = 0; i < 4; ++i) {
    const int oi = t + i * 256;
    const int row = oi >> 6, col = oi & 63;
    float M = fmaxf(fmaxf(pmL[0][row], pmL[1][row]), fmaxf(pmL[2][row], pmL[3][row]));
    float L = 0.f, acc = 0.f;
#pragma unroll
    for (int s2 = 0; s2 < 4; ++s2) {
      const float e = __expf(pmL[s2][row] - M);
      L += plsL[s2][row] * e;
      acc += poL[s2][row][col] * e;
    }
    head[((long long)b * 2048 + q0 + row) * 64 + col] = f2bf(acc / L);
  }
}

// ---------------- fused head@Wdsum + bias + residual + LN2 ------------------
__global__ __launch_bounds__(256)
void hwd_ln_k(const u16* __restrict__ head, const u16* __restrict__ Wdst,
              const float* __restrict__ bd, float* __restrict__ h,
              const float* __restrict__ g, const float* __restrict__ be,
              u16* __restrict__ z)
{
  const int t = threadIdx.x, w = t >> 6, l = t & 63;
  const int l15 = l & 15, l16 = l >> 4;
  const int r0 = blockIdx.x << 4;
  const int c0 = w << 8;
  bf16x8 af[2];
#pragma unroll
  for (int kk = 0; kk < 2; ++kk)
    af[kk] = *(const bf16x8*)&head[(long long)(r0 + l15) * 64 + kk * 32 + l16 * 8];
  f32x4 acc[16];
#pragma unroll
  for (int nf = 0; nf < 16; ++nf) {
    const int e = c0 + nf * 16 + l15;
    f32x4 a = {0.f, 0.f, 0.f, 0.f};
    bf16x8 b0 = *(const bf16x8*)&Wdst[e * 64 + l16 * 8];
    bf16x8 b1 = *(const bf16x8*)&Wdst[e * 64 + 32 + l16 * 8];
    a = __builtin_amdgcn_mfma_f32_16x16x32_bf16(af[0], b0, a, 0, 0, 0);
    a = __builtin_amdgcn_mfma_f32_16x16x32_bf16(af[1], b1, a, 0, 0, 0);
    acc[nf] = a;
  }
  float ps[4] = {0.f, 0.f, 0.f, 0.f}, pq[4] = {0.f, 0.f, 0.f, 0.f};
#pragma unroll
  for (int nf = 0; nf < 16; ++nf) {
    const int col = c0 + nf * 16 + l15;
#pragma unroll
    for (int r = 0; r < 4; ++r) {
      const long long row = r0 + l16 * 4 + r;
      float v = h[row * 1024 + col] + acc[nf][r] + bd[col];
      acc[nf][r] = v;
      ps[r] += v; pq[r] += v * v;
    }
  }
#pragma unroll
  for (int r = 0; r < 4; ++r) {
#pragma unroll
    for (int msk = 1; msk < 16; msk <<= 1) {
      ps[r] += __shfl_xor(ps[r], msk);
      pq[r] += __shfl_xor(pq[r], msk);
    }
  }
  __shared__ float S[4][16], Q[4][16];
  if (l15 == 0) {
#pragma unroll
    for (int r = 0; r < 4; ++r) { S[w][l16 * 4 + r] = ps[r]; Q[w][l16 * 4 + r] = pq[r]; }
  }
  __syncthreads();
  float mu[4], rstd[4];
#pragma unroll
  for (int r = 0; r < 4; ++r) {
    const int ri = l16 * 4 + r;
    const float s = S[0][ri] + S[1][ri] + S[2][ri] + S[3][ri];
    const float q = Q[0][ri] + Q[1][ri] + Q[2][ri] + Q[3][ri];
    mu[r] = s * (1.f / 1024.f);
    rstd[r] = rsqrtf(q * (1.f / 1024.f) - mu[r] * mu[r] + 1e-5f);
  }
#pragma unroll
  for (int nf = 0; nf < 16; ++nf) {
    const int col = c0 + nf * 16 + l15;
    const float gc = g[col], bc = be[col];
#pragma unroll
    for (int r = 0; r < 4; ++r) {
      const long long row = r0 + l16 * 4 + r;
      h[row * 1024 + col] = acc[nf][r];
      z[row * 1024 + col] = f2bf((acc[nf][r] - mu[r]) * rstd[r] * gc + bc);
    }
  }
}

// LayerNorm over rows of 1024 f32 -> bf16 out (layer-0 only)
__global__ __launch_bounds__(256)
void ln_k(const float* __restrict__ x, const float* __restrict__ g,
          const float* __restrict__ b, u16* __restrict__ z)
{
  const long long row = blockIdx.x;
  f32x4 v = ((const f32x4*)(x + row * 1024))[threadIdx.x];
  float s = v[0] + v[1] + v[2] + v[3];
  float q = v[0] * v[0] + v[1] * v[1] + v[2] * v[2] + v[3] * v[3];
#pragma unroll
  for (int o = 32; o; o >>= 1) { s += __shfl_down(s, o); q += __shfl_down(q, o); }
  __shared__ float rs_[4], rq_[4];
  const int l = threadIdx.x & 63, w = threadIdx.x >> 6;
  if (l == 0) { rs_[w] = s; rq_[w] = q; }
  __syncthreads();
  s = rs_[0] + rs_[1] + rs_[2] + rs_[3];
  q = rq_[0] + rq_[1] + rq_[2] + rq_[3];
  const float mu = s * (1.f / 1024.f);
  const float rstd = rsqrtf(q * (1.f / 1024.f) - mu * mu + 1e-5f);
  const f32x4 gv = ((const f32x4*)g)[threadIdx.x];
  const f32x4 bv = ((const f32x4*)b)[threadIdx.x];
  u16x4 o4;
#pragma unroll
  for (int e = 0; e < 4; ++e) o4[e] = f2bf((v[e] - mu) * rstd * gv[e] + bv[e]);
  ((u16x4*)(z + row * 1024))[threadIdx.x] = o4;
}

// fused: hnew = h + sum_{s<4} bf16partial_s + c2 ; MODE0: h=hnew, z=LN(hnew);
// MODE1: z=bf16(hnew) (h dead)
template<int MODE>
__global__ __launch_bounds__(256)
void reduce_ln_k(const u16* __restrict__ p, float* __restrict__ h,
                 const float* __restrict__ c2, const float* __restrict__ g,
                 const float* __restrict__ b, u16* __restrict__ z)
{
  const long long row = blockIdx.x;
  const int t = threadIdx.x;
  const long long i4 = (row << 8) + t;
  f32x4 v = ((const f32x4*)h)[i4] + ((const f32x4*)c2)[t];
#pragma unroll
  for (int s = 0; s < 4; ++s) {
    u16x4 pv = ((const u16x4*)p)[i4 + (long long)s * 1048576];
#pragma unroll
    for (int e = 0; e < 4; ++e) v[e] += bf2f(pv[e]);
  }
  u16x4 o4;
  if (MODE == 1) {
#pragma unroll
    for (int e = 0; e < 4; ++e) o4[e] = f2bf(v[e]);
  } else {
    ((f32x4*)h)[i4] = v;
    float s = v[0] + v[1] + v[2] + v[3];
    float q = v[0] * v[0] + v[1] * v[1] + v[2] * v[2] + v[3] * v[3];
#pragma unroll
    for (int o = 32; o; o >>= 1) { s += __shfl_down(s, o); q += __shfl_down(q, o); }
    __shared__ float rs_[4], rq_[4];
    const int l = t & 63, w = t >> 6;
    if (l == 0) { rs_[w] = s; rq_[w] = q; }
    __syncthreads();
    s = rs_[0] + rs_[1] + rs_[2] + rs_[3];
    q = rq_[0] + rq_[1] + rq_[2] + rq_[3];
    const float mu = s * (1.f / 1024.f);
    const float rstd = rsqrtf(q * (1.f / 1024.f) - mu * mu + 1e-5f);
    const f32x4 gv = ((const f32x4*)g)[t];
    const f32x4 bv = ((const f32x4*)b)[t];
#pragma unroll
    for (int e = 0; e < 4; ++e) o4[e] = f2bf((v[e] - mu) * rstd * gv[e] + bv[e]);
  }
  ((u16x4*)z)[i4] = o4;
}

__global__ __launch_bounds__(256)
void gather_k(const int* __restrict__ x, const float* __restrict__ emb, float* __restrict__ h)
{
  const long long tok = blockIdx.x;
  const long long r = (long long)x[tok] << 8;
  ((f32x4*)h)[(tok << 8) + threadIdx.x] = ((const f32x4*)emb)[r + threadIdx.x];
}

// f32 [R][C] -> bf16 [C][R]
__global__ __launch_bounds__(256)
void tcast_k(const float* __restrict__ in, u16* __restrict__ out, int R, int C)
{
  __shared__ float tile[32][33];
  const int tx = threadIdx.x & 31, ty = threadIdx.x >> 5;
  const long long r0 = (long long)blockIdx.y << 5, c0 = (long long)blockIdx.x << 5;
#pragma unroll
  for (int yy = 0; yy < 32; yy += 8)
    tile[ty + yy][tx] = in[(r0 + ty + yy) * C + c0 + tx];
  __syncthreads();
#pragma unroll
  for (int yy = 0; yy < 32; yy += 8)
    out[(c0 + ty + yy) * R + r0 + tx] = f2bf(tile[tx][ty + yy]);
}

__global__ __launch_bounds__(256)
void wqkv_k(const float* __restrict__ Wq, const float* __restrict__ Wk,
            const float* __restrict__ Wv, u16* __restrict__ o)
{
  const int n = blockIdx.y;
  const long long e = (long long)blockIdx.x * 256 + threadIdx.x;
  float v = 0.f;
  if (n < 64)       v = Wq[e * 64 + n];
  else if (n < 128) v = Wk[e * 64 + (n - 64)];
  else if (n < 192) v = Wv[e * 64 + (n - 128)];
  o[(long long)n * 1024 + e] = f2bf(v);
}

__global__ __launch_bounds__(256)
void bqkv_k(const float* __restrict__ bq, const float* __restrict__ bk,
            const float* __restrict__ bv, float* __restrict__ o)
{
  const int n = threadIdx.x;
  float v = 0.f;
  if (n < 64)       v = bq[n];
  else if (n < 128) v = bk[n - 64];
  else if (n < 192) v = bv[n - 128];
  o[n] = v;
}

__global__ __launch_bounds__(256)
void wdsum_k(const float* __restrict__ Wd, u16* __restrict__ o)
{
  const int i = blockIdx.x * 256 + threadIdx.x;
  const int a = i & 63, e = i >> 6;
  float s = 0.f;
#pragma unroll
  for (int hh = 0; hh < 16; ++hh) s += Wd[(long long)(hh * 64 + a) * 1024 + e];
  o[i] = f2bf(s);
}

// qkv = bf16(p0+p1+bqkv) from bf16 partials, plus vT scatter for v-cols
__global__ __launch_bounds__(256)
void reduce_qkv(const u16* __restrict__ p, const float* __restrict__ bqkv,
                u16* __restrict__ qkv, u16* __restrict__ vT)
{
  const long long i4 = (long long)blockIdx.x * 256 + threadIdx.x;
  const int c4 = (int)(i4 & 63);
  const long long row = i4 >> 6;
  u16x4 a = ((const u16x4*)p)[i4];
  u16x4 b2 = ((const u16x4*)p)[i4 + 262144];
  const f32x4 bb = ((const f32x4*)bqkv)[c4];
  u16x4 o;
#pragma unroll
  for (int e = 0; e < 4; ++e) o[e] = f2bf(bf2f(a[e]) + bf2f(b2[e]) + bb[e]);
  ((u16x4*)qkv)[i4] = o;
  if (c4 >= 32 && c4 < 48) {
    const long long b = row >> 11, sidx = row & 2047;
#pragma unroll
    for (int e = 0; e < 4; ++e) {
      const int aa = (c4 - 32) * 4 + e;
      vT[(b * 64 + aa) * 2048 + sidx] = o[e];
    }
  }
}

extern "C" void kernel_launch(void* const* d_in, const int* in_sizes, int n_in,
                              void* d_out, int out_size, void* d_ws, size_t ws_size,
                              hipStream_t stream) {
  const int*   x   = (const int*)d_in[0];
  const float* emb = (const float*)d_in[1];
  const float* Wq  = (const float*)d_in[2];
  const float* bq  = (const float*)d_in[3];
  const float* Wk  = (const float*)d_in[4];
  const float* bk  = (const float*)d_in[5];
  const float* Wv  = (const float*)d_in[6];
  const float* bv  = (const float*)d_in[7];
  const float* Wd  = (const float*)d_in[8];
  const float* bd  = (const float*)d_in[9];
  const float* g1  = (const float*)d_in[10];
  const float* be1 = (const float*)d_in[11];
  const float* g2  = (const float*)d_in[12];
  const float* be2 = (const float*)d_in[13];
  const float* W1  = (const float*)d_in[14];
  const float* c1  = (const float*)d_in[15];
  const float* W2  = (const float*)d_in[16];
  const float* c2  = (const float*)d_in[17];
  const float* Wfc = (const float*)d_in[18];
  const float* bfc = (const float*)d_in[19];
  float* out = (float*)d_out;

  char* ws = (char*)d_ws;
  size_t off = 0;
  auto alloc = [&](size_t bytes) { void* p = ws + off; off = (off + bytes + 255) & ~(size_t)255; return p; };
  float*  h     = (float*) alloc(4096ull * 1024 * 4);
  u16*    z     = (u16*)   alloc(4096ull * 1024 * 2);
  u16*    qkv   = (u16*)   alloc(4096ull * 256 * 2);
  u16*    vT    = (u16*)   alloc(2ull * 64 * 2048 * 2);
  u16*    head  = (u16*)   alloc(4096ull * 64 * 2);
  u16*    mid   = (u16*)   alloc(4096ull * 4096 * 2);
  // SCR aliasing (lifetimes disjoint): partQb [QKV->reduce]; partF [FFN2->reduce_ln]
  char*   SCR   = (char*)  alloc(2ull * 4096 * 1024 * 4);
  u16*    partQb= (u16*)SCR;
  u16*    partF = (u16*)SCR;
  u16*    Wqkvt = (u16*)   alloc(256ull * 1024 * 2);
  float*  bqkv  = (float*) alloc(256 * 4);
  u16*    Wdst  = (u16*)   alloc(1024ull * 64 * 2);
  u16*    W1t   = (u16*)   alloc(4096ull * 1024 * 2);
  u16*    W2t   = (u16*)   alloc(1024ull * 4096 * 2);
  u16*    Wfct  = (u16*)   alloc(32000ull * 1024 * 2);

  // ---- prep (every launch; no caching allowed) ----
  gather_k<<<4096, 256, 0, stream>>>(x, emb, h);
  wqkv_k<<<dim3(4, 256), 256, 0, stream>>>(Wq, Wk, Wv, Wqkvt);
  bqkv_k<<<1, 256, 0, stream>>>(bq, bk, bv, bqkv);
  wdsum_k<<<256, 256, 0, stream>>>(Wd, Wdst);
  tcast_k<<<dim3(128, 32), 256, 0, stream>>>(W1, W1t, 1024, 4096);
  tcast_k<<<dim3(32, 128), 256, 0, stream>>>(W2, W2t, 4096, 1024);
  tcast_k<<<dim3(1000, 32), 256, 0, stream>>>(Wfc, Wfct, 1024, 32000);

  for (int layer = 0; layer < 8; ++layer) {
    if (layer == 0)
      ln_k<<<4096, 256, 0, stream>>>(h, g1, be1, z);
    // partQb[z] = bf16(z1 @ Wqkv^T) (split-K x2, K=512 each) -- legacy engine
    gemm_bt<2><<<dim3(64, 1, 2), 256, 0, stream>>>(z, Wqkvt, nullptr, partQb, nullptr, 1.f,
        512, 1024, 1024, 256, 32, 32, 2, 0, 0, 1048576);
    reduce_qkv<<<1024, 256, 0, stream>>>(partQb, bqkv, qkv, vT);
    // fused attention: 4-wave split-KV, in-LDS LSE merge
    flash4_k<<<256, 256, 0, stream>>>(qkv, vT, head);
    // fused: h += head@Wdsum^T + bd ; z = LN2(h)
    hwd_ln_k<<<256, 256, 0, stream>>>(head, Wdst, bd, h, g2, be2, z);
    // mid = relu(z2 @ W1 + c1) -- gemm2b (2 blocks/CU)
    gemm2b<3><<<dim3(256, 1, 1), 512, 0, stream>>>(z, W1t, nullptr, mid, c1, 1.f,
        1024, 1024, 1024, 4096, 16, 16, 1, 0, 0, 0);
    // partF[sp] = bf16(mid @ W2^T) (split-K x4, K=1024 each)
    gemm2b<2><<<dim3(64, 1, 4), 512, 0, stream>>>(mid, W2t, nullptr, partF, nullptr, 1.f,
        1024, 4096, 4096, 1024, 16, 16, 4, 0, 0, 4194304);
    if (layer < 7)
      reduce_ln_k<0><<<4096, 256, 0, stream>>>(partF, h, c2, g1, be1, z);
    else
      reduce_ln_k<1><<<4096, 256, 0, stream>>>(partF, h, c2, nullptr, nullptr, z);
  }
  // out = hb @ Wfc + bfc -- gemm2b, grouped gm=8
  gemm2b<0><<<dim3(2000, 1, 1), 512, 0, stream>>>(z, Wfct, out, nullptr, bfc, 1.f,
      1024, 1024, 1024, 32000, 16, 8, 1, 0, 0, 0);
}

// Round 12
// 1573.599 us; speedup vs baseline: 1.0385x; 1.0385x over previous
//
#include <hip/hip_runtime.h>

typedef unsigned short u16;
typedef __attribute__((ext_vector_type(4))) float f32x4;
typedef __attribute__((ext_vector_type(8))) __bf16 bf16x8;
typedef __attribute__((ext_vector_type(4))) unsigned short u16x4;

static __device__ __forceinline__ u16 f2bf(float f) {
  union { float f; unsigned u; } v; v.f = f;
  unsigned r = v.u + 0x7fffu + ((v.u >> 16) & 1u);
  return (u16)(r >> 16);
}
static __device__ __forceinline__ float bf2f(u16 u) {
  union { unsigned u; float f; } x; x.u = ((unsigned)u) << 16; return x.f;
}

#define GLD_LDS(g, l) __builtin_amdgcn_global_load_lds( \
    (const __attribute__((address_space(1))) void*)(g), \
    (__attribute__((address_space(3))) void*)(l), 16, 0, 0)

// ---------------------------------------------------------------------------
// R5/R10 engine (measured best; frozen): 256x256 BK=64 8-wave, 2-phase/K-tile,
// T2 swizzle (conflicts=0), counted vmcnt(8), setprio. 128 KB dynamic LDS.
// EPI: 0 = Cf = alpha*acc + bias; 2 = Cb = bf16(acc+bias); 3 = bf16 relu.
// ---------------------------------------------------------------------------
template<int EPI>
__global__ __launch_bounds__(512, 2)
void gemm8p(const u16* __restrict__ A, const u16* __restrict__ B,
            float* __restrict__ Cf, u16* __restrict__ Cb,
            const float* __restrict__ bias, float alpha,
            int K, int lda, int ldb, int ldc, int mtiles, int gm, int nsplit,
            long long sA, long long sB, long long sC)
{
  extern __shared__ u16 lds8[];
  const int t = threadIdx.x;
  const int w = t >> 6, l = t & 63;
  const int l15 = l & 15, l16 = l >> 4;
  const int wr = w >> 2, wc = w & 3;

  int wg = blockIdx.x;
  const int nwg = gridDim.x;
  {
    const int q = nwg >> 3, r = nwg & 7;
    const int xcd = wg & 7, loc = wg >> 3;
    wg = (xcd < r ? xcd * (q + 1) : r * (q + 1) + (xcd - r) * q) + loc;
  }
  const int ntiles = nwg / mtiles;
  const int gsz = gm * ntiles;
  const int gi = wg / gsz;
  const int rr = wg - gi * gsz;
  const int nt = rr / gm;
  const int mt = gi * gm + (rr - nt * gm);
  const int m0 = mt << 8, n0 = nt << 8;

  const int bz = blockIdx.z;
  int batch = bz, sp = 0;
  if (nsplit > 1) { batch = bz / nsplit; sp = bz - batch * nsplit; }
  const u16* Ab = A + (long long)batch * sA + (long long)sp * K;
  const u16* Bb = B + (long long)batch * sB + (long long)sp * K;
  const long long cbase = (long long)bz * sC;

  const int srow = t >> 3;
  const int scol = (((t & 7) ^ (srow & 7)) << 3);
  const u16* gA[4]; const u16* gB[4];
#pragma unroll
  for (int i = 0; i < 4; ++i) {
    gA[i] = Ab + (long long)(m0 + i * 64 + srow) * lda + scol;
    gB[i] = Bb + (long long)(n0 + i * 64 + srow) * ldb + scol;
  }
  const int ldst = w << 9;

  auto STAGE = [&](int buf) {
#pragma unroll
    for (int i = 0; i < 4; ++i) {
      GLD_LDS(gA[i], &lds8[buf * 16384 + i * 4096 + ldst]);
      gA[i] += 64;
    }
#pragma unroll
    for (int i = 0; i < 4; ++i) {
      GLD_LDS(gB[i], &lds8[32768 + buf * 16384 + i * 4096 + ldst]);
      gB[i] += 64;
    }
  };

  STAGE(0);
  STAGE(1);

  f32x4 acc[8][4] = {};
  const int nkt = K >> 6;
  const int aRow = wr * 128 + l15;
  const int bRow = wc * 64 + l15;
  const int swz = l15 & 7;

  for (int kt = 0; kt < nkt; ++kt) {
    const int buf = kt & 1;
    if (kt < nkt - 1) asm volatile("s_waitcnt vmcnt(8)" ::: "memory");
    else              asm volatile("s_waitcnt vmcnt(0)" ::: "memory");
    __builtin_amdgcn_s_barrier();
    __builtin_amdgcn_sched_barrier(0);

    const int abase = buf * 16384;
    const int bbase = 32768 + buf * 16384;
    bf16x8 af[4][2], bf[4][2];
#pragma unroll
    for (int mf = 0; mf < 4; ++mf)
#pragma unroll
      for (int kk = 0; kk < 2; ++kk)
        af[mf][kk] = *(const bf16x8*)&lds8[abase + (aRow + mf * 16) * 64 + ((((kk << 2) + l16)) ^ swz) * 8];
#pragma unroll
    for (int nf = 0; nf < 4; ++nf)
#pragma unroll
      for (int kk = 0; kk < 2; ++kk)
        bf[nf][kk] = *(const bf16x8*)&lds8[bbase + (bRow + nf * 16) * 64 + ((((kk << 2) + l16)) ^ swz) * 8];

    __builtin_amdgcn_s_setprio(1);
#pragma unroll
    for (int mf = 0; mf < 4; ++mf)
#pragma unroll
      for (int nf = 0; nf < 4; ++nf)
#pragma unroll
        for (int kk = 0; kk < 2; ++kk)
          acc[mf][nf] = __builtin_amdgcn_mfma_f32_16x16x32_bf16(af[mf][kk], bf[nf][kk], acc[mf][nf], 0, 0, 0);
    __builtin_amdgcn_s_setprio(0);

    bf16x8 ah[4][2];
#pragma unroll
    for (int mf = 0; mf < 4; ++mf)
#pragma unroll
      for (int kk = 0; kk < 2; ++kk)
        ah[mf][kk] = *(const bf16x8*)&lds8[abase + (aRow + 64 + mf * 16) * 64 + ((((kk << 2) + l16)) ^ swz) * 8];

    asm volatile("s_waitcnt lgkmcnt(0)" ::: "memory");
    __builtin_amdgcn_s_barrier();
    __builtin_amdgcn_sched_barrier(0);
    if (kt + 2 < nkt) STAGE(buf);

    __builtin_amdgcn_s_setprio(1);
#pragma unroll
    for (int mf = 0; mf < 4; ++mf)
#pragma unroll
      for (int nf = 0; nf < 4; ++nf)
#pragma unroll
        for (int kk = 0; kk < 2; ++kk)
          acc[mf + 4][nf] = __builtin_amdgcn_mfma_f32_16x16x32_bf16(ah[mf][kk], bf[nf][kk], acc[mf + 4][nf], 0, 0, 0);
    __builtin_amdgcn_s_setprio(0);
  }

#pragma unroll
  for (int mf = 0; mf < 8; ++mf) {
    const int rbase = m0 + wr * 128 + mf * 16 + l16 * 4;
#pragma unroll
    for (int nf = 0; nf < 4; ++nf) {
      const int col = n0 + wc * 64 + nf * 16 + l15;
      const float bv = bias ? bias[col] : 0.f;
#pragma unroll
      for (int r = 0; r < 4; ++r) {
        const long long idx = cbase + (long long)(rbase + r) * ldc + col;
        const float v = acc[mf][nf][r];
        if (EPI == 0)      Cf[idx] = alpha * v + bv;
        else if (EPI == 2) Cb[idx] = f2bf(v + bv);
        else               { float x = v + bv; Cb[idx] = f2bf(x > 0.f ? x : 0.f); }
      }
    }
  }
}

// ---- legacy 128x128 engine (small shapes: QKV) ----
template<int EPI>
__global__ __launch_bounds__(256)
void gemm_bt(const u16* __restrict__ A, const u16* __restrict__ B,
             float* __restrict__ Cf, u16* __restrict__ Cb,
             const float* __restrict__ bias, float alpha,
             int K, int lda, int ldb, int ldc, int mtiles, int gm, int nsplit,
             long long sA, long long sB, long long sC)
{
  __shared__ u16 ldsA[128 * 32];
  __shared__ u16 ldsB[128 * 32];
  const int t = threadIdx.x;
  const int w = t >> 6, l = t & 63;

  int wg = blockIdx.x;
  const int nwg = gridDim.x;
  {
    const int q = nwg >> 3, r = nwg & 7;
    const int xcd = wg & 7, loc = wg >> 3;
    wg = (xcd < r ? xcd * (q + 1) : r * (q + 1) + (xcd - r) * q) + loc;
  }
  const int ntiles = nwg / mtiles;
  const int gsz = gm * ntiles;
  const int gi = wg / gsz;
  const int rr = wg - gi * gsz;
  const int nt = rr / gm;
  const int mt = gi * gm + (rr - nt * gm);
  const int m0 = mt << 7, n0 = nt << 7;

  const int bzRaw = blockIdx.z;
  int batch = bzRaw, sp = 0;
  if (nsplit > 1) { batch = bzRaw / nsplit; sp = bzRaw - batch * nsplit; }
  const u16* Ab = A + (long long)batch * sA + (long long)sp * K;
  const u16* Bb = B + (long long)batch * sB + (long long)sp * K;
  const long long cbase = (long long)bzRaw * sC;

  const int wr = (w >> 1) << 6, wc = (w & 1) << 6;
  const int l15 = l & 15, l16 = l >> 4;
  f32x4 acc[4][4] = {};

  for (int k0 = 0; k0 < K; k0 += 32) {
#pragma unroll
    for (int r = 0; r < 2; ++r) {
      const int o = (r << 12) + (t << 4);
      const int row = o >> 6;
      const int cole = (o & 63) >> 1;
      GLD_LDS(Ab + (long long)(m0 + row) * lda + k0 + cole, &ldsA[(r << 11) + (w << 9)]);
      GLD_LDS(Bb + (long long)(n0 + row) * ldb + k0 + cole, &ldsB[(r << 11) + (w << 9)]);
    }
    __syncthreads();
    bf16x8 af[4], bg[4];
#pragma unroll
    for (int i = 0; i < 4; ++i) {
      af[i] = *(const bf16x8*)&ldsA[(wr + i * 16 + l15) * 32 + l16 * 8];
      bg[i] = *(const bf16x8*)&ldsB[(wc + i * 16 + l15) * 32 + l16 * 8];
    }
#pragma unroll
    for (int i = 0; i < 4; ++i)
#pragma unroll
      for (int j = 0; j < 4; ++j)
        acc[i][j] = __builtin_amdgcn_mfma_f32_16x16x32_bf16(af[i], bg[j], acc[i][j], 0, 0, 0);
    __syncthreads();
  }

#pragma unroll
  for (int i = 0; i < 4; ++i) {
    const int rbase = m0 + wr + i * 16 + l16 * 4;
#pragma unroll
    for (int j = 0; j < 4; ++j) {
      const int col = n0 + wc + j * 16 + l15;
      const float bv = bias ? bias[col] : 0.f;
#pragma unroll
      for (int r = 0; r < 4; ++r) {
        const long long idx = cbase + (long long)(rbase + r) * ldc + col;
        const float v = acc[i][j][r];
        if (EPI == 0)      Cf[idx] = alpha * v + bv;
        else if (EPI == 1) Cf[idx] += v + bv;
        else if (EPI == 2) Cb[idx] = f2bf(v + bv);
        else               { float x = v + bv; Cb[idx] = f2bf(x > 0.f ? x : 0.f); }
      }
    }
  }
}

// ---------------- fused flash attention: 4 waves split-KV, in-LDS merge -----
__device__ __forceinline__ void fstep(
    const bf16x8 (&ck)[4][2], const bf16x8 (&cv)[4][2],
    bf16x8 (&nk)[4][2], bf16x8 (&nv)[4][2],
    const bf16x8 (&qf)[2], float (&m)[4], float (&ls)[4], f32x4 (&o)[4],
    const u16* qb, const u16* vb, int kvn, u16* pl, int l15, int l16)
{
  f32x4 s[4] = {};
#pragma unroll
  for (int ni = 0; ni < 4; ++ni)
#pragma unroll
    for (int kk = 0; kk < 2; ++kk)
      s[ni] = __builtin_amdgcn_mfma_f32_16x16x32_bf16(qf[kk], ck[ni][kk], s[ni], 0, 0, 0);
#pragma unroll
  for (int ni = 0; ni < 4; ++ni)
#pragma unroll
    for (int kk = 0; kk < 2; ++kk)
      nk[ni][kk] = *(const bf16x8*)(qb + (kvn + ni * 16 + l15) * 256 + 64 + kk * 32 + l16 * 8);
#pragma unroll
  for (int ni = 0; ni < 4; ++ni) s[ni] *= 0.125f;
  float al[4], ps[4];
#pragma unroll
  for (int r = 0; r < 4; ++r) {
    float v = fmaxf(fmaxf(s[0][r], s[1][r]), fmaxf(s[2][r], s[3][r]));
    v = fmaxf(v, __shfl_xor(v, 1)); v = fmaxf(v, __shfl_xor(v, 2));
    v = fmaxf(v, __shfl_xor(v, 4)); v = fmaxf(v, __shfl_xor(v, 8));
    const float mn = fmaxf(m[r], v);
    al[r] = __expf(m[r] - mn);
    m[r] = mn;
    ps[r] = 0.f;
  }
#pragma unroll
  for (int ni = 0; ni < 4; ++ni)
#pragma unroll
    for (int r = 0; r < 4; ++r) {
      const float p = __expf(s[ni][r] - m[r]);
      ps[r] += p;
      pl[(l16 * 4 + r) * 72 + ni * 16 + l15] = f2bf(p);
    }
#pragma unroll
  for (int r = 0; r < 4; ++r) {
    float t = ps[r];
    t += __shfl_xor(t, 1); t += __shfl_xor(t, 2);
    t += __shfl_xor(t, 4); t += __shfl_xor(t, 8);
    ls[r] = ls[r] * al[r] + t;
  }
#pragma unroll
  for (int nd = 0; nd < 4; ++nd)
#pragma unroll
    for (int r = 0; r < 4; ++r) o[nd][r] *= al[r];
  bf16x8 pa[2];
#pragma unroll
  for (int kk = 0; kk < 2; ++kk)
    pa[kk] = *(const bf16x8*)&pl[l15 * 72 + kk * 32 + l16 * 8];
#pragma unroll
  for (int nd = 0; nd < 4; ++nd)
#pragma unroll
    for (int kk = 0; kk < 2; ++kk)
      o[nd] = __builtin_amdgcn_mfma_f32_16x16x32_bf16(pa[kk], cv[nd][kk], o[nd], 0, 0, 0);
#pragma unroll
  for (int nd = 0; nd < 4; ++nd)
#pragma unroll
    for (int kk = 0; kk < 2; ++kk)
      nv[nd][kk] = *(const bf16x8*)(vb + (nd * 16 + l15) * 2048 + kvn + kk * 32 + l16 * 8);
}

__global__ __launch_bounds__(256)
void flash4_k(const u16* __restrict__ qkv, const u16* __restrict__ vT,
              u16* __restrict__ head)
{
  __shared__ u16 plbuf[4][16 * 72];
  __shared__ float poL[4][16][64];
  __shared__ float pmL[4][16], plsL[4][16];
  const int t = threadIdx.x, sp = t >> 6, l = t & 63;
  const int l15 = l & 15, l16 = l >> 4;
  const int b = blockIdx.x >> 7, q0 = (blockIdx.x & 127) << 4;
  const int kvb = sp << 9;
  const u16* qb = qkv + (long long)b * 2048 * 256;
  const u16* vb = vT + (long long)b * 64 * 2048;
  u16* pl = &plbuf[sp][0];
  bf16x8 qf[2];
#pragma unroll
  for (int kk = 0; kk < 2; ++kk)
    qf[kk] = *(const bf16x8*)(qb + (q0 + l15) * 256 + kk * 32 + l16 * 8);
  float m[4], ls[4];
  f32x4 o[4] = {};
#pragma unroll
  for (int r = 0; r < 4; ++r) { m[r] = -1e30f; ls[r] = 0.f; }
  bf16x8 ka[4][2], va[4][2], kb[4][2], vb2[4][2];
#pragma unroll
  for (int ni = 0; ni < 4; ++ni)
#pragma unroll
    for (int kk = 0; kk < 2; ++kk) {
      ka[ni][kk] = *(const bf16x8*)(qb + (kvb + ni * 16 + l15) * 256 + 64 + kk * 32 + l16 * 8);
      va[ni][kk] = *(const bf16x8*)(vb + (ni * 16 + l15) * 2048 + kvb + kk * 32 + l16 * 8);
    }
  for (int ti = 0; ti < 8; ti += 2) {
    const int n1 = kvb + (ti + 1 < 8 ? (ti + 1) * 64 : 7 * 64);
    const int n2 = kvb + (ti + 2 < 8 ? (ti + 2) * 64 : 7 * 64);
    fstep(ka, va, kb, vb2, qf, m, ls, o, qb, vb, n1, pl, l15, l16);
    fstep(kb, vb2, ka, va, qf, m, ls, o, qb, vb, n2, pl, l15, l16);
  }
#pragma unroll
  for (int nd = 0; nd < 4; ++nd)
#pragma unroll
    for (int r = 0; r < 4; ++r)
      poL[sp][l16 * 4 + r][nd * 16 + l15] = o[nd][r];
  if (l15 == 0) {
#pragma unroll
    for (int r = 0; r < 4; ++r) {
      pmL[sp][l16 * 4 + r] = m[r];
      plsL[sp][l16 * 4 + r] = ls[r];
    }
  }
  __syncthreads();
#pragma unroll
  for (int i = 0; i < 4; ++i) {
    const int oi = t + i * 256;
    const int row = oi >> 6, col = oi & 63;
    float M = fmaxf(fmaxf(pmL[0][row], pmL[1][row]), fmaxf(pmL[2][row], pmL[3][row]));
    float L = 0.f, acc = 0.f;
#pragma unroll
    for (int s2 = 0; s2 < 4; ++s2) {
      const float e = __expf(pmL[s2][row] - M);
      L += plsL[s2][row] * e;
      acc += poL[s2][row][col] * e;
    }
    head[((long long)b * 2048 + q0 + row) * 64 + col] = f2bf(acc / L);
  }
}

// ---------------- fused head@Wdsum + bias + residual + LN2 ------------------
__global__ __launch_bounds__(256)
void hwd_ln_k(const u16* __restrict__ head, const u16* __restrict__ Wdst,
              const float* __restrict__ bd, float* __restrict__ h,
              const float* __restrict__ g, const float* __restrict__ be,
              u16* __restrict__ z)
{
  const int t = threadIdx.x, w = t >> 6, l = t & 63;
  const int l15 = l & 15, l16 = l >> 4;
  const int r0 = blockIdx.x << 4;
  const int c0 = w << 8;
  bf16x8 af[2];
#pragma unroll
  for (int kk = 0; kk < 2; ++kk)
    af[kk] = *(const bf16x8*)&head[(long long)(r0 + l15) * 64 + kk * 32 + l16 * 8];
  f32x4 acc[16];
#pragma unroll
  for (int nf = 0; nf < 16; ++nf) {
    const int e = c0 + nf * 16 + l15;
    f32x4 a = {0.f, 0.f, 0.f, 0.f};
    bf16x8 b0 = *(const bf16x8*)&Wdst[e * 64 + l16 * 8];
    bf16x8 b1 = *(const bf16x8*)&Wdst[e * 64 + 32 + l16 * 8];
    a = __builtin_amdgcn_mfma_f32_16x16x32_bf16(af[0], b0, a, 0, 0, 0);
    a = __builtin_amdgcn_mfma_f32_16x16x32_bf16(af[1], b1, a, 0, 0, 0);
    acc[nf] = a;
  }
  float ps[4] = {0.f, 0.f, 0.f, 0.f}, pq[4] = {0.f, 0.f, 0.f, 0.f};
#pragma unroll
  for (int nf = 0; nf < 16; ++nf) {
    const int col = c0 + nf * 16 + l15;
#pragma unroll
    for (int r = 0; r < 4; ++r) {
      const long long row = r0 + l16 * 4 + r;
      float v = h[row * 1024 + col] + acc[nf][r] + bd[col];
      acc[nf][r] = v;
      ps[r] += v; pq[r] += v * v;
    }
  }
#pragma unroll
  for (int r = 0; r < 4; ++r) {
#pragma unroll
    for (int msk = 1; msk < 16; msk <<= 1) {
      ps[r] += __shfl_xor(ps[r], msk);
      pq[r] += __shfl_xor(pq[r], msk);
    }
  }
  __shared__ float S[4][16], Q[4][16];
  if (l15 == 0) {
#pragma unroll
    for (int r = 0; r < 4; ++r) { S[w][l16 * 4 + r] = ps[r]; Q[w][l16 * 4 + r] = pq[r]; }
  }
  __syncthreads();
  float mu[4], rstd[4];
#pragma unroll
  for (int r = 0; r < 4; ++r) {
    const int ri = l16 * 4 + r;
    const float s = S[0][ri] + S[1][ri] + S[2][ri] + S[3][ri];
    const float q = Q[0][ri] + Q[1][ri] + Q[2][ri] + Q[3][ri];
    mu[r] = s * (1.f / 1024.f);
    rstd[r] = rsqrtf(q * (1.f / 1024.f) - mu[r] * mu[r] + 1e-5f);
  }
#pragma unroll
  for (int nf = 0; nf < 16; ++nf) {
    const int col = c0 + nf * 16 + l15;
    const float gc = g[col], bc = be[col];
#pragma unroll
    for (int r = 0; r < 4; ++r) {
      const long long row = r0 + l16 * 4 + r;
      h[row * 1024 + col] = acc[nf][r];
      z[row * 1024 + col] = f2bf((acc[nf][r] - mu[r]) * rstd[r] * gc + bc);
    }
  }
}

// LayerNorm over rows of 1024 f32 -> bf16 out (layer-0 only)
__global__ __launch_bounds__(256)
void ln_k(const float* __restrict__ x, const float* __restrict__ g,
          const float* __restrict__ b, u16* __restrict__ z)
{
  const long long row = blockIdx.x;
  f32x4 v = ((const f32x4*)(x + row * 1024))[threadIdx.x];
  float s = v[0] + v[1] + v[2] + v[3];
  float q = v[0] * v[0] + v[1] * v[1] + v[2] * v[2] + v[3] * v[3];
#pragma unroll
  for (int o = 32; o; o >>= 1) { s += __shfl_down(s, o); q += __shfl_down(q, o); }
  __shared__ float rs_[4], rq_[4];
  const int l = threadIdx.x & 63, w = threadIdx.x >> 6;
  if (l == 0) { rs_[w] = s; rq_[w] = q; }
  __syncthreads();
  s = rs_[0] + rs_[1] + rs_[2] + rs_[3];
  q = rq_[0] + rq_[1] + rq_[2] + rq_[3];
  const float mu = s * (1.f / 1024.f);
  const float rstd = rsqrtf(q * (1.f / 1024.f) - mu * mu + 1e-5f);
  const f32x4 gv = ((const f32x4*)g)[threadIdx.x];
  const f32x4 bv = ((const f32x4*)b)[threadIdx.x];
  u16x4 o4;
#pragma unroll
  for (int e = 0; e < 4; ++e) o4[e] = f2bf((v[e] - mu) * rstd * gv[e] + bv[e]);
  ((u16x4*)(z + row * 1024))[threadIdx.x] = o4;
}

// fused: hnew = h + sum_{s<4} bf16partial_s + c2 ; MODE0: h=hnew, z=LN(hnew);
// MODE1: z=bf16(hnew)
template<int MODE>
__global__ __launch_bounds__(256)
void reduce_ln_k(const u16* __restrict__ p, float* __restrict__ h,
                 const float* __restrict__ c2, const float* __restrict__ g,
                 const float* __restrict__ b, u16* __restrict__ z)
{
  const long long row = blockIdx.x;
  const int t = threadIdx.x;
  const long long i4 = (row << 8) + t;
  f32x4 v = ((const f32x4*)h)[i4] + ((const f32x4*)c2)[t];
#pragma unroll
  for (int s = 0; s < 4; ++s) {
    u16x4 pv = ((const u16x4*)p)[i4 + (long long)s * 1048576];
#pragma unroll
    for (int e = 0; e < 4; ++e) v[e] += bf2f(pv[e]);
  }
  u16x4 o4;
  if (MODE == 1) {
#pragma unroll
    for (int e = 0; e < 4; ++e) o4[e] = f2bf(v[e]);
  } else {
    ((f32x4*)h)[i4] = v;
    float s = v[0] + v[1] + v[2] + v[3];
    float q = v[0] * v[0] + v[1] * v[1] + v[2] * v[2] + v[3] * v[3];
#pragma unroll
    for (int o = 32; o; o >>= 1) { s += __shfl_down(s, o); q += __shfl_down(q, o); }
    __shared__ float rs_[4], rq_[4];
    const int l = t & 63, w = t >> 6;
    if (l == 0) { rs_[w] = s; rq_[w] = q; }
    __syncthreads();
    s = rs_[0] + rs_[1] + rs_[2] + rs_[3];
    q = rq_[0] + rq_[1] + rq_[2] + rq_[3];
    const float mu = s * (1.f / 1024.f);
    const float rstd = rsqrtf(q * (1.f / 1024.f) - mu * mu + 1e-5f);
    const f32x4 gv = ((const f32x4*)g)[t];
    const f32x4 bv = ((const f32x4*)b)[t];
#pragma unroll
    for (int e = 0; e < 4; ++e) o4[e] = f2bf((v[e] - mu) * rstd * gv[e] + bv[e]);
  }
  ((u16x4*)z)[i4] = o4;
}

__global__ __launch_bounds__(256)
void gather_k(const int* __restrict__ x, const float* __restrict__ emb, float* __restrict__ h)
{
  const long long tok = blockIdx.x;
  const long long r = (long long)x[tok] << 8;
  ((f32x4*)h)[(tok << 8) + threadIdx.x] = ((const f32x4*)emb)[r + threadIdx.x];
}

// f32 [R][C] -> bf16 [C][R]
__global__ __launch_bounds__(256)
void tcast_k(const float* __restrict__ in, u16* __restrict__ out, int R, int C)
{
  __shared__ float tile[32][33];
  const int tx = threadIdx.x & 31, ty = threadIdx.x >> 5;
  const long long r0 = (long long)blockIdx.y << 5, c0 = (long long)blockIdx.x << 5;
#pragma unroll
  for (int yy = 0; yy < 32; yy += 8)
    tile[ty + yy][tx] = in[(r0 + ty + yy) * C + c0 + tx];
  __syncthreads();
#pragma unroll
  for (int yy = 0; yy < 32; yy += 8)
    out[(c0 + ty + yy) * R + r0 + tx] = f2bf(tile[tx][ty + yy]);
}

__global__ __launch_bounds__(256)
void wqkv_k(const float* __restrict__ Wq, const float* __restrict__ Wk,
            const float* __restrict__ Wv, u16* __restrict__ o)
{
  const int n = blockIdx.y;
  const long long e = (long long)blockIdx.x * 256 + threadIdx.x;
  float v = 0.f;
  if (n < 64)       v = Wq[e * 64 + n];
  else if (n < 128) v = Wk[e * 64 + (n - 64)];
  else if (n < 192) v = Wv[e * 64 + (n - 128)];
  o[(long long)n * 1024 + e] = f2bf(v);
}

__global__ __launch_bounds__(256)
void bqkv_k(const float* __restrict__ bq, const float* __restrict__ bk,
            const float* __restrict__ bv, float* __restrict__ o)
{
  const int n = threadIdx.x;
  float v = 0.f;
  if (n < 64)       v = bq[n];
  else if (n < 128) v = bk[n - 64];
  else if (n < 192) v = bv[n - 128];
  o[n] = v;
}

__global__ __launch_bounds__(256)
void wdsum_k(const float* __restrict__ Wd, u16* __restrict__ o)
{
  const int i = blockIdx.x * 256 + threadIdx.x;
  const int a = i & 63, e = i >> 6;
  float s = 0.f;
#pragma unroll
  for (int hh = 0; hh < 16; ++hh) s += Wd[(long long)(hh * 64 + a) * 1024 + e];
  o[i] = f2bf(s);
}

// qkv = bf16(p0+p1+bqkv) from bf16 partials, plus vT scatter for v-cols
__global__ __launch_bounds__(256)
void reduce_qkv(const u16* __restrict__ p, const float* __restrict__ bqkv,
                u16* __restrict__ qkv, u16* __restrict__ vT)
{
  const long long i4 = (long long)blockIdx.x * 256 + threadIdx.x;
  const int c4 = (int)(i4 & 63);
  const long long row = i4 >> 6;
  u16x4 a = ((const u16x4*)p)[i4];
  u16x4 b2 = ((const u16x4*)p)[i4 + 262144];
  const f32x4 bb = ((const f32x4*)bqkv)[c4];
  u16x4 o;
#pragma unroll
  for (int e = 0; e < 4; ++e) o[e] = f2bf(bf2f(a[e]) + bf2f(b2[e]) + bb[e]);
  ((u16x4*)qkv)[i4] = o;
  if (c4 >= 32 && c4 < 48) {
    const long long b = row >> 11, sidx = row & 2047;
#pragma unroll
    for (int e = 0; e < 4; ++e) {
      const int aa = (c4 - 32) * 4 + e;
      vT[(b * 64 + aa) * 2048 + sidx] = o[e];
    }
  }
}

extern "C" void kernel_launch(void* const* d_in, const int* in_sizes, int n_in,
                              void* d_out, int out_size, void* d_ws, size_t ws_size,
                              hipStream_t stream) {
  const int*   x   = (const int*)d_in[0];
  const float* emb = (const float*)d_in[1];
  const float* Wq  = (const float*)d_in[2];
  const float* bq  = (const float*)d_in[3];
  const float* Wk  = (const float*)d_in[4];
  const float* bk  = (const float*)d_in[5];
  const float* Wv  = (const float*)d_in[6];
  const float* bv  = (const float*)d_in[7];
  const float* Wd  = (const float*)d_in[8];
  const float* bd  = (const float*)d_in[9];
  const float* g1  = (const float*)d_in[10];
  const float* be1 = (const float*)d_in[11];
  const float* g2  = (const float*)d_in[12];
  const float* be2 = (const float*)d_in[13];
  const float* W1  = (const float*)d_in[14];
  const float* c1  = (const float*)d_in[15];
  const float* W2  = (const float*)d_in[16];
  const float* c2  = (const float*)d_in[17];
  const float* Wfc = (const float*)d_in[18];
  const float* bfc = (const float*)d_in[19];
  float* out = (float*)d_out;

  hipFuncSetAttribute(reinterpret_cast<const void*>(gemm8p<0>),
                      hipFuncAttributeMaxDynamicSharedMemorySize, 131072);
  hipFuncSetAttribute(reinterpret_cast<const void*>(gemm8p<2>),
                      hipFuncAttributeMaxDynamicSharedMemorySize, 131072);
  hipFuncSetAttribute(reinterpret_cast<const void*>(gemm8p<3>),
                      hipFuncAttributeMaxDynamicSharedMemorySize, 131072);

  char* ws = (char*)d_ws;
  size_t off = 0;
  auto alloc = [&](size_t bytes) { void* p = ws + off; off = (off + bytes + 255) & ~(size_t)255; return p; };
  float*  h     = (float*) alloc(4096ull * 1024 * 4);
  u16*    z     = (u16*)   alloc(4096ull * 1024 * 2);
  u16*    qkv   = (u16*)   alloc(4096ull * 256 * 2);
  u16*    vT    = (u16*)   alloc(2ull * 64 * 2048 * 2);
  u16*    head  = (u16*)   alloc(4096ull * 64 * 2);
  u16*    mid   = (u16*)   alloc(4096ull * 4096 * 2);
  // SCR aliasing (lifetimes disjoint): partQb [QKV->reduce]; partF [FFN2->reduce_ln]
  char*   SCR   = (char*)  alloc(2ull * 4096 * 1024 * 4);
  u16*    partQb= (u16*)SCR;
  u16*    partF = (u16*)SCR;
  u16*    Wqkvt = (u16*)   alloc(256ull * 1024 * 2);
  float*  bqkv  = (float*) alloc(256 * 4);
  u16*    Wdst  = (u16*)   alloc(1024ull * 64 * 2);
  u16*    W1t   = (u16*)   alloc(4096ull * 1024 * 2);
  u16*    W2t   = (u16*)   alloc(1024ull * 4096 * 2);
  u16*    Wfct  = (u16*)   alloc(32000ull * 1024 * 2);

  // ---- prep (every launch; no caching allowed) ----
  gather_k<<<4096, 256, 0, stream>>>(x, emb, h);
  wqkv_k<<<dim3(4, 256), 256, 0, stream>>>(Wq, Wk, Wv, Wqkvt);
  bqkv_k<<<1, 256, 0, stream>>>(bq, bk, bv, bqkv);
  wdsum_k<<<256, 256, 0, stream>>>(Wd, Wdst);
  tcast_k<<<dim3(128, 32), 256, 0, stream>>>(W1, W1t, 1024, 4096);
  tcast_k<<<dim3(32, 128), 256, 0, stream>>>(W2, W2t, 4096, 1024);
  tcast_k<<<dim3(1000, 32), 256, 0, stream>>>(Wfc, Wfct, 1024, 32000);

  for (int layer = 0; layer < 8; ++layer) {
    if (layer == 0)
      ln_k<<<4096, 256, 0, stream>>>(h, g1, be1, z);
    // partQb[z] = bf16(z1 @ Wqkv^T) (split-K x2, K=512 each) -- legacy engine
    gemm_bt<2><<<dim3(64, 1, 2), 256, 0, stream>>>(z, Wqkvt, nullptr, partQb, nullptr, 1.f,
        512, 1024, 1024, 256, 32, 32, 2, 0, 0, 1048576);
    reduce_qkv<<<1024, 256, 0, stream>>>(partQb, bqkv, qkv, vT);
    // fused attention: 4-wave split-KV, in-LDS LSE merge
    flash4_k<<<256, 256, 0, stream>>>(qkv, vT, head);
    // fused: h += head@Wdsum^T + bd ; z = LN2(h)
    hwd_ln_k<<<256, 256, 0, stream>>>(head, Wdst, bd, h, g2, be2, z);
    // mid = relu(z2 @ W1 + c1) -- R5 engine
    gemm8p<3><<<dim3(256, 1, 1), 512, 131072, stream>>>(z, W1t, nullptr, mid, c1, 1.f,
        1024, 1024, 1024, 4096, 16, 16, 1, 0, 0, 0);
    // partF[sp] = bf16(mid @ W2^T) (split-K x4, K=1024 each) -- R5 engine
    gemm8p<2><<<dim3(64, 1, 4), 512, 131072, stream>>>(mid, W2t, nullptr, partF, nullptr, 1.f,
        1024, 4096, 4096, 1024, 16, 16, 4, 0, 0, 4194304);
    if (layer < 7)
      reduce_ln_k<0><<<4096, 256, 0, stream>>>(partF, h, c2, g1, be1, z);
    else
      reduce_ln_k<1><<<4096, 256, 0, stream>>>(partF, h, c2, nullptr, nullptr, z);
  }
  // out = hb @ Wfc + bfc -- R5 engine, grouped gm=16 (single mt-group:
  // B=Wfct fetched once, A L2-resident across nt sweep)
  gemm8p<0><<<dim3(2000, 1, 1), 512, 131072, stream>>>(z, Wfct, out, nullptr, bfc, 1.f,
      1024, 1024, 1024, 32000, 16, 16, 1, 0, 0, 0);
}

// Round 13
// 1563.406 us; speedup vs baseline: 1.0453x; 1.0065x over previous
//
#include <hip/hip_runtime.h>

typedef unsigned short u16;
typedef __attribute__((ext_vector_type(4))) float f32x4;
typedef __attribute__((ext_vector_type(8))) __bf16 bf16x8;
typedef __attribute__((ext_vector_type(4))) unsigned short u16x4;

static __device__ __forceinline__ u16 f2bf(float f) {
  union { float f; unsigned u; } v; v.f = f;
  unsigned r = v.u + 0x7fffu + ((v.u >> 16) & 1u);
  return (u16)(r >> 16);
}
static __device__ __forceinline__ float bf2f(u16 u) {
  union { unsigned u; float f; } x; x.u = ((unsigned)u) << 16; return x.f;
}

#define GLD_LDS(g, l) __builtin_amdgcn_global_load_lds( \
    (const __attribute__((address_space(1))) void*)(g), \
    (__attribute__((address_space(3))) void*)(l), 16, 0, 0)

// ---------------------------------------------------------------------------
// R5/R10 engine (measured best; frozen): 256x256 BK=64 8-wave, 2-phase/K-tile,
// T2 swizzle (conflicts=0), counted vmcnt(8), setprio. 128 KB dynamic LDS.
// EPI: 0 = Cf = alpha*acc + bias; 2 = Cb = bf16(acc+bias); 3 = bf16 relu.
// ---------------------------------------------------------------------------
template<int EPI>
__global__ __launch_bounds__(512, 2)
void gemm8p(const u16* __restrict__ A, const u16* __restrict__ B,
            float* __restrict__ Cf, u16* __restrict__ Cb,
            const float* __restrict__ bias, float alpha,
            int K, int lda, int ldb, int ldc, int mtiles, int gm, int nsplit,
            long long sA, long long sB, long long sC)
{
  extern __shared__ u16 lds8[];
  const int t = threadIdx.x;
  const int w = t >> 6, l = t & 63;
  const int l15 = l & 15, l16 = l >> 4;
  const int wr = w >> 2, wc = w & 3;

  int wg = blockIdx.x;
  const int nwg = gridDim.x;
  {
    const int q = nwg >> 3, r = nwg & 7;
    const int xcd = wg & 7, loc = wg >> 3;
    wg = (xcd < r ? xcd * (q + 1) : r * (q + 1) + (xcd - r) * q) + loc;
  }
  const int ntiles = nwg / mtiles;
  const int gsz = gm * ntiles;
  const int gi = wg / gsz;
  const int rr = wg - gi * gsz;
  const int nt = rr / gm;
  const int mt = gi * gm + (rr - nt * gm);
  const int m0 = mt << 8, n0 = nt << 8;

  const int bz = blockIdx.z;
  int batch = bz, sp = 0;
  if (nsplit > 1) { batch = bz / nsplit; sp = bz - batch * nsplit; }
  const u16* Ab = A + (long long)batch * sA + (long long)sp * K;
  const u16* Bb = B + (long long)batch * sB + (long long)sp * K;
  const long long cbase = (long long)bz * sC;

  const int srow = t >> 3;
  const int scol = (((t & 7) ^ (srow & 7)) << 3);
  const u16* gA[4]; const u16* gB[4];
#pragma unroll
  for (int i = 0; i < 4; ++i) {
    gA[i] = Ab + (long long)(m0 + i * 64 + srow) * lda + scol;
    gB[i] = Bb + (long long)(n0 + i * 64 + srow) * ldb + scol;
  }
  const int ldst = w << 9;

  auto STAGE = [&](int buf) {
#pragma unroll
    for (int i = 0; i < 4; ++i) {
      GLD_LDS(gA[i], &lds8[buf * 16384 + i * 4096 + ldst]);
      gA[i] += 64;
    }
#pragma unroll
    for (int i = 0; i < 4; ++i) {
      GLD_LDS(gB[i], &lds8[32768 + buf * 16384 + i * 4096 + ldst]);
      gB[i] += 64;
    }
  };

  STAGE(0);
  STAGE(1);

  f32x4 acc[8][4] = {};
  const int nkt = K >> 6;
  const int aRow = wr * 128 + l15;
  const int bRow = wc * 64 + l15;
  const int swz = l15 & 7;

  for (int kt = 0; kt < nkt; ++kt) {
    const int buf = kt & 1;
    if (kt < nkt - 1) asm volatile("s_waitcnt vmcnt(8)" ::: "memory");
    else              asm volatile("s_waitcnt vmcnt(0)" ::: "memory");
    __builtin_amdgcn_s_barrier();
    __builtin_amdgcn_sched_barrier(0);

    const int abase = buf * 16384;
    const int bbase = 32768 + buf * 16384;
    bf16x8 af[4][2], bf[4][2];
#pragma unroll
    for (int mf = 0; mf < 4; ++mf)
#pragma unroll
      for (int kk = 0; kk < 2; ++kk)
        af[mf][kk] = *(const bf16x8*)&lds8[abase + (aRow + mf * 16) * 64 + ((((kk << 2) + l16)) ^ swz) * 8];
#pragma unroll
    for (int nf = 0; nf < 4; ++nf)
#pragma unroll
      for (int kk = 0; kk < 2; ++kk)
        bf[nf][kk] = *(const bf16x8*)&lds8[bbase + (bRow + nf * 16) * 64 + ((((kk << 2) + l16)) ^ swz) * 8];

    __builtin_amdgcn_s_setprio(1);
#pragma unroll
    for (int mf = 0; mf < 4; ++mf)
#pragma unroll
      for (int nf = 0; nf < 4; ++nf)
#pragma unroll
        for (int kk = 0; kk < 2; ++kk)
          acc[mf][nf] = __builtin_amdgcn_mfma_f32_16x16x32_bf16(af[mf][kk], bf[nf][kk], acc[mf][nf], 0, 0, 0);
    __builtin_amdgcn_s_setprio(0);

    bf16x8 ah[4][2];
#pragma unroll
    for (int mf = 0; mf < 4; ++mf)
#pragma unroll
      for (int kk = 0; kk < 2; ++kk)
        ah[mf][kk] = *(const bf16x8*)&lds8[abase + (aRow + 64 + mf * 16) * 64 + ((((kk << 2) + l16)) ^ swz) * 8];

    asm volatile("s_waitcnt lgkmcnt(0)" ::: "memory");
    __builtin_amdgcn_s_barrier();
    __builtin_amdgcn_sched_barrier(0);
    if (kt + 2 < nkt) STAGE(buf);

    __builtin_amdgcn_s_setprio(1);
#pragma unroll
    for (int mf = 0; mf < 4; ++mf)
#pragma unroll
      for (int nf = 0; nf < 4; ++nf)
#pragma unroll
        for (int kk = 0; kk < 2; ++kk)
          acc[mf + 4][nf] = __builtin_amdgcn_mfma_f32_16x16x32_bf16(ah[mf][kk], bf[nf][kk], acc[mf + 4][nf], 0, 0, 0);
    __builtin_amdgcn_s_setprio(0);
  }

#pragma unroll
  for (int mf = 0; mf < 8; ++mf) {
    const int rbase = m0 + wr * 128 + mf * 16 + l16 * 4;
#pragma unroll
    for (int nf = 0; nf < 4; ++nf) {
      const int col = n0 + wc * 64 + nf * 16 + l15;
      const float bv = bias ? bias[col] : 0.f;
#pragma unroll
      for (int r = 0; r < 4; ++r) {
        const long long idx = cbase + (long long)(rbase + r) * ldc + col;
        const float v = acc[mf][nf][r];
        if (EPI == 0)      Cf[idx] = alpha * v + bv;
        else if (EPI == 2) Cb[idx] = f2bf(v + bv);
        else               { float x = v + bv; Cb[idx] = f2bf(x > 0.f ? x : 0.f); }
      }
    }
  }
}

// ---- legacy 128x128 engine (small shapes: QKV) ----
template<int EPI>
__global__ __launch_bounds__(256)
void gemm_bt(const u16* __restrict__ A, const u16* __restrict__ B,
             float* __restrict__ Cf, u16* __restrict__ Cb,
             const float* __restrict__ bias, float alpha,
             int K, int lda, int ldb, int ldc, int mtiles, int gm, int nsplit,
             long long sA, long long sB, long long sC)
{
  __shared__ u16 ldsA[128 * 32];
  __shared__ u16 ldsB[128 * 32];
  const int t = threadIdx.x;
  const int w = t >> 6, l = t & 63;

  int wg = blockIdx.x;
  const int nwg = gridDim.x;
  {
    const int q = nwg >> 3, r = nwg & 7;
    const int xcd = wg & 7, loc = wg >> 3;
    wg = (xcd < r ? xcd * (q + 1) : r * (q + 1) + (xcd - r) * q) + loc;
  }
  const int ntiles = nwg / mtiles;
  const int gsz = gm * ntiles;
  const int gi = wg / gsz;
  const int rr = wg - gi * gsz;
  const int nt = rr / gm;
  const int mt = gi * gm + (rr - nt * gm);
  const int m0 = mt << 7, n0 = nt << 7;

  const int bzRaw = blockIdx.z;
  int batch = bzRaw, sp = 0;
  if (nsplit > 1) { batch = bzRaw / nsplit; sp = bzRaw - batch * nsplit; }
  const u16* Ab = A + (long long)batch * sA + (long long)sp * K;
  const u16* Bb = B + (long long)batch * sB + (long long)sp * K;
  const long long cbase = (long long)bzRaw * sC;

  const int wr = (w >> 1) << 6, wc = (w & 1) << 6;
  const int l15 = l & 15, l16 = l >> 4;
  f32x4 acc[4][4] = {};

  for (int k0 = 0; k0 < K; k0 += 32) {
#pragma unroll
    for (int r = 0; r < 2; ++r) {
      const int o = (r << 12) + (t << 4);
      const int row = o >> 6;
      const int cole = (o & 63) >> 1;
      GLD_LDS(Ab + (long long)(m0 + row) * lda + k0 + cole, &ldsA[(r << 11) + (w << 9)]);
      GLD_LDS(Bb + (long long)(n0 + row) * ldb + k0 + cole, &ldsB[(r << 11) + (w << 9)]);
    }
    __syncthreads();
    bf16x8 af[4], bg[4];
#pragma unroll
    for (int i = 0; i < 4; ++i) {
      af[i] = *(const bf16x8*)&ldsA[(wr + i * 16 + l15) * 32 + l16 * 8];
      bg[i] = *(const bf16x8*)&ldsB[(wc + i * 16 + l15) * 32 + l16 * 8];
    }
#pragma unroll
    for (int i = 0; i < 4; ++i)
#pragma unroll
      for (int j = 0; j < 4; ++j)
        acc[i][j] = __builtin_amdgcn_mfma_f32_16x16x32_bf16(af[i], bg[j], acc[i][j], 0, 0, 0);
    __syncthreads();
  }

#pragma unroll
  for (int i = 0; i < 4; ++i) {
    const int rbase = m0 + wr + i * 16 + l16 * 4;
#pragma unroll
    for (int j = 0; j < 4; ++j) {
      const int col = n0 + wc + j * 16 + l15;
      const float bv = bias ? bias[col] : 0.f;
#pragma unroll
      for (int r = 0; r < 4; ++r) {
        const long long idx = cbase + (long long)(rbase + r) * ldc + col;
        const float v = acc[i][j][r];
        if (EPI == 0)      Cf[idx] = alpha * v + bv;
        else if (EPI == 1) Cf[idx] += v + bv;
        else if (EPI == 2) Cb[idx] = f2bf(v + bv);
        else               { float x = v + bv; Cb[idx] = f2bf(x > 0.f ? x : 0.f); }
      }
    }
  }
}

// ---------------- fused flash attention: 4 waves split-KV, in-LDS merge -----
__device__ __forceinline__ void fstep(
    const bf16x8 (&ck)[4][2], const bf16x8 (&cv)[4][2],
    bf16x8 (&nk)[4][2], bf16x8 (&nv)[4][2],
    const bf16x8 (&qf)[2], float (&m)[4], float (&ls)[4], f32x4 (&o)[4],
    const u16* qb, const u16* vb, int kvn, u16* pl, int l15, int l16)
{
  f32x4 s[4] = {};
#pragma unroll
  for (int ni = 0; ni < 4; ++ni)
#pragma unroll
    for (int kk = 0; kk < 2; ++kk)
      s[ni] = __builtin_amdgcn_mfma_f32_16x16x32_bf16(qf[kk], ck[ni][kk], s[ni], 0, 0, 0);
#pragma unroll
  for (int ni = 0; ni < 4; ++ni)
#pragma unroll
    for (int kk = 0; kk < 2; ++kk)
      nk[ni][kk] = *(const bf16x8*)(qb + (kvn + ni * 16 + l15) * 256 + 64 + kk * 32 + l16 * 8);
#pragma unroll
  for (int ni = 0; ni < 4; ++ni) s[ni] *= 0.125f;
  float al[4], ps[4];
#pragma unroll
  for (int r = 0; r < 4; ++r) {
    float v = fmaxf(fmaxf(s[0][r], s[1][r]), fmaxf(s[2][r], s[3][r]));
    v = fmaxf(v, __shfl_xor(v, 1)); v = fmaxf(v, __shfl_xor(v, 2));
    v = fmaxf(v, __shfl_xor(v, 4)); v = fmaxf(v, __shfl_xor(v, 8));
    const float mn = fmaxf(m[r], v);
    al[r] = __expf(m[r] - mn);
    m[r] = mn;
    ps[r] = 0.f;
  }
#pragma unroll
  for (int ni = 0; ni < 4; ++ni)
#pragma unroll
    for (int r = 0; r < 4; ++r) {
      const float p = __expf(s[ni][r] - m[r]);
      ps[r] += p;
      pl[(l16 * 4 + r) * 72 + ni * 16 + l15] = f2bf(p);
    }
#pragma unroll
  for (int r = 0; r < 4; ++r) {
    float t = ps[r];
    t += __shfl_xor(t, 1); t += __shfl_xor(t, 2);
    t += __shfl_xor(t, 4); t += __shfl_xor(t, 8);
    ls[r] = ls[r] * al[r] + t;
  }
#pragma unroll
  for (int nd = 0; nd < 4; ++nd)
#pragma unroll
    for (int r = 0; r < 4; ++r) o[nd][r] *= al[r];
  bf16x8 pa[2];
#pragma unroll
  for (int kk = 0; kk < 2; ++kk)
    pa[kk] = *(const bf16x8*)&pl[l15 * 72 + kk * 32 + l16 * 8];
#pragma unroll
  for (int nd = 0; nd < 4; ++nd)
#pragma unroll
    for (int kk = 0; kk < 2; ++kk)
      o[nd] = __builtin_amdgcn_mfma_f32_16x16x32_bf16(pa[kk], cv[nd][kk], o[nd], 0, 0, 0);
#pragma unroll
  for (int nd = 0; nd < 4; ++nd)
#pragma unroll
    for (int kk = 0; kk < 2; ++kk)
      nv[nd][kk] = *(const bf16x8*)(vb + (nd * 16 + l15) * 2048 + kvn + kk * 32 + l16 * 8);
}

__global__ __launch_bounds__(256)
void flash4_k(const u16* __restrict__ qkv, const u16* __restrict__ vT,
              u16* __restrict__ head)
{
  __shared__ u16 plbuf[4][16 * 72];
  __shared__ float poL[4][16][64];
  __shared__ float pmL[4][16], plsL[4][16];
  const int t = threadIdx.x, sp = t >> 6, l = t & 63;
  const int l15 = l & 15, l16 = l >> 4;
  const int b = blockIdx.x >> 7, q0 = (blockIdx.x & 127) << 4;
  const int kvb = sp << 9;
  const u16* qb = qkv + (long long)b * 2048 * 256;
  const u16* vb = vT + (long long)b * 64 * 2048;
  u16* pl = &plbuf[sp][0];
  bf16x8 qf[2];
#pragma unroll
  for (int kk = 0; kk < 2; ++kk)
    qf[kk] = *(const bf16x8*)(qb + (q0 + l15) * 256 + kk * 32 + l16 * 8);
  float m[4], ls[4];
  f32x4 o[4] = {};
#pragma unroll
  for (int r = 0; r < 4; ++r) { m[r] = -1e30f; ls[r] = 0.f; }
  bf16x8 ka[4][2], va[4][2], kb[4][2], vb2[4][2];
#pragma unroll
  for (int ni = 0; ni < 4; ++ni)
#pragma unroll
    for (int kk = 0; kk < 2; ++kk) {
      ka[ni][kk] = *(const bf16x8*)(qb + (kvb + ni * 16 + l15) * 256 + 64 + kk * 32 + l16 * 8);
      va[ni][kk] = *(const bf16x8*)(vb + (ni * 16 + l15) * 2048 + kvb + kk * 32 + l16 * 8);
    }
  for (int ti = 0; ti < 8; ti += 2) {
    const int n1 = kvb + (ti + 1 < 8 ? (ti + 1) * 64 : 7 * 64);
    const int n2 = kvb + (ti + 2 < 8 ? (ti + 2) * 64 : 7 * 64);
    fstep(ka, va, kb, vb2, qf, m, ls, o, qb, vb, n1, pl, l15, l16);
    fstep(kb, vb2, ka, va, qf, m, ls, o, qb, vb, n2, pl, l15, l16);
  }
#pragma unroll
  for (int nd = 0; nd < 4; ++nd)
#pragma unroll
    for (int r = 0; r < 4; ++r)
      poL[sp][l16 * 4 + r][nd * 16 + l15] = o[nd][r];
  if (l15 == 0) {
#pragma unroll
    for (int r = 0; r < 4; ++r) {
      pmL[sp][l16 * 4 + r] = m[r];
      plsL[sp][l16 * 4 + r] = ls[r];
    }
  }
  __syncthreads();
#pragma unroll
  for (int i = 0; i < 4; ++i) {
    const int oi = t + i * 256;
    const int row = oi >> 6, col = oi & 63;
    float M = fmaxf(fmaxf(pmL[0][row], pmL[1][row]), fmaxf(pmL[2][row], pmL[3][row]));
    float L = 0.f, acc = 0.f;
#pragma unroll
    for (int s2 = 0; s2 < 4; ++s2) {
      const float e = __expf(pmL[s2][row] - M);
      L += plsL[s2][row] * e;
      acc += poL[s2][row][col] * e;
    }
    head[((long long)b * 2048 + q0 + row) * 64 + col] = f2bf(acc / L);
  }
}

// ---------------- fused head@Wdsum + bias + residual + LN2 ------------------
__global__ __launch_bounds__(256)
void hwd_ln_k(const u16* __restrict__ head, const u16* __restrict__ Wdst,
              const float* __restrict__ bd, float* __restrict__ h,
              const float* __restrict__ g, const float* __restrict__ be,
              u16* __restrict__ z)
{
  const int t = threadIdx.x, w = t >> 6, l = t & 63;
  const int l15 = l & 15, l16 = l >> 4;
  const int r0 = blockIdx.x << 4;
  const int c0 = w << 8;
  bf16x8 af[2];
#pragma unroll
  for (int kk = 0; kk < 2; ++kk)
    af[kk] = *(const bf16x8*)&head[(long long)(r0 + l15) * 64 + kk * 32 + l16 * 8];
  f32x4 acc[16];
#pragma unroll
  for (int nf = 0; nf < 16; ++nf) {
    const int e = c0 + nf * 16 + l15;
    f32x4 a = {0.f, 0.f, 0.f, 0.f};
    bf16x8 b0 = *(const bf16x8*)&Wdst[e * 64 + l16 * 8];
    bf16x8 b1 = *(const bf16x8*)&Wdst[e * 64 + 32 + l16 * 8];
    a = __builtin_amdgcn_mfma_f32_16x16x32_bf16(af[0], b0, a, 0, 0, 0);
    a = __builtin_amdgcn_mfma_f32_16x16x32_bf16(af[1], b1, a, 0, 0, 0);
    acc[nf] = a;
  }
  float ps[4] = {0.f, 0.f, 0.f, 0.f}, pq[4] = {0.f, 0.f, 0.f, 0.f};
#pragma unroll
  for (int nf = 0; nf < 16; ++nf) {
    const int col = c0 + nf * 16 + l15;
#pragma unroll
    for (int r = 0; r < 4; ++r) {
      const long long row = r0 + l16 * 4 + r;
      float v = h[row * 1024 + col] + acc[nf][r] + bd[col];
      acc[nf][r] = v;
      ps[r] += v; pq[r] += v * v;
    }
  }
#pragma unroll
  for (int r = 0; r < 4; ++r) {
#pragma unroll
    for (int msk = 1; msk < 16; msk <<= 1) {
      ps[r] += __shfl_xor(ps[r], msk);
      pq[r] += __shfl_xor(pq[r], msk);
    }
  }
  __shared__ float S[4][16], Q[4][16];
  if (l15 == 0) {
#pragma unroll
    for (int r = 0; r < 4; ++r) { S[w][l16 * 4 + r] = ps[r]; Q[w][l16 * 4 + r] = pq[r]; }
  }
  __syncthreads();
  float mu[4], rstd[4];
#pragma unroll
  for (int r = 0; r < 4; ++r) {
    const int ri = l16 * 4 + r;
    const float s = S[0][ri] + S[1][ri] + S[2][ri] + S[3][ri];
    const float q = Q[0][ri] + Q[1][ri] + Q[2][ri] + Q[3][ri];
    mu[r] = s * (1.f / 1024.f);
    rstd[r] = rsqrtf(q * (1.f / 1024.f) - mu[r] * mu[r] + 1e-5f);
  }
#pragma unroll
  for (int nf = 0; nf < 16; ++nf) {
    const int col = c0 + nf * 16 + l15;
    const float gc = g[col], bc = be[col];
#pragma unroll
    for (int r = 0; r < 4; ++r) {
      const long long row = r0 + l16 * 4 + r;
      h[row * 1024 + col] = acc[nf][r];
      z[row * 1024 + col] = f2bf((acc[nf][r] - mu[r]) * rstd[r] * gc + bc);
    }
  }
}

// LayerNorm over rows of 1024 f32 -> bf16 out (layer-0 only)
__global__ __launch_bounds__(256)
void ln_k(const float* __restrict__ x, const float* __restrict__ g,
          const float* __restrict__ b, u16* __restrict__ z)
{
  const long long row = blockIdx.x;
  f32x4 v = ((const f32x4*)(x + row * 1024))[threadIdx.x];
  float s = v[0] + v[1] + v[2] + v[3];
  float q = v[0] * v[0] + v[1] * v[1] + v[2] * v[2] + v[3] * v[3];
#pragma unroll
  for (int o = 32; o; o >>= 1) { s += __shfl_down(s, o); q += __shfl_down(q, o); }
  __shared__ float rs_[4], rq_[4];
  const int l = threadIdx.x & 63, w = threadIdx.x >> 6;
  if (l == 0) { rs_[w] = s; rq_[w] = q; }
  __syncthreads();
  s = rs_[0] + rs_[1] + rs_[2] + rs_[3];
  q = rq_[0] + rq_[1] + rq_[2] + rq_[3];
  const float mu = s * (1.f / 1024.f);
  const float rstd = rsqrtf(q * (1.f / 1024.f) - mu * mu + 1e-5f);
  const f32x4 gv = ((const f32x4*)g)[threadIdx.x];
  const f32x4 bv = ((const f32x4*)b)[threadIdx.x];
  u16x4 o4;
#pragma unroll
  for (int e = 0; e < 4; ++e) o4[e] = f2bf((v[e] - mu) * rstd * gv[e] + bv[e]);
  ((u16x4*)(z + row * 1024))[threadIdx.x] = o4;
}

// fused: hnew = h + sum_{s<4} bf16partial_s + c2 ; MODE0: h=hnew, z=LN(hnew);
// MODE1: z=bf16(hnew)
template<int MODE>
__global__ __launch_bounds__(256)
void reduce_ln_k(const u16* __restrict__ p, float* __restrict__ h,
                 const float* __restrict__ c2, const float* __restrict__ g,
                 const float* __restrict__ b, u16* __restrict__ z)
{
  const long long row = blockIdx.x;
  const int t = threadIdx.x;
  const long long i4 = (row << 8) + t;
  f32x4 v = ((const f32x4*)h)[i4] + ((const f32x4*)c2)[t];
#pragma unroll
  for (int s = 0; s < 4; ++s) {
    u16x4 pv = ((const u16x4*)p)[i4 + (long long)s * 1048576];
#pragma unroll
    for (int e = 0; e < 4; ++e) v[e] += bf2f(pv[e]);
  }
  u16x4 o4;
  if (MODE == 1) {
#pragma unroll
    for (int e = 0; e < 4; ++e) o4[e] = f2bf(v[e]);
  } else {
    ((f32x4*)h)[i4] = v;
    float s = v[0] + v[1] + v[2] + v[3];
    float q = v[0] * v[0] + v[1] * v[1] + v[2] * v[2] + v[3] * v[3];
#pragma unroll
    for (int o = 32; o; o >>= 1) { s += __shfl_down(s, o); q += __shfl_down(q, o); }
    __shared__ float rs_[4], rq_[4];
    const int l = t & 63, w = t >> 6;
    if (l == 0) { rs_[w] = s; rq_[w] = q; }
    __syncthreads();
    s = rs_[0] + rs_[1] + rs_[2] + rs_[3];
    q = rq_[0] + rq_[1] + rq_[2] + rq_[3];
    const float mu = s * (1.f / 1024.f);
    const float rstd = rsqrtf(q * (1.f / 1024.f) - mu * mu + 1e-5f);
    const f32x4 gv = ((const f32x4*)g)[t];
    const f32x4 bv = ((const f32x4*)b)[t];
#pragma unroll
    for (int e = 0; e < 4; ++e) o4[e] = f2bf((v[e] - mu) * rstd * gv[e] + bv[e]);
  }
  ((u16x4*)z)[i4] = o4;
}

__global__ __launch_bounds__(256)
void gather_k(const int* __restrict__ x, const float* __restrict__ emb, float* __restrict__ h)
{
  const long long tok = blockIdx.x;
  const long long r = (long long)x[tok] << 8;
  ((f32x4*)h)[(tok << 8) + threadIdx.x] = ((const f32x4*)emb)[r + threadIdx.x];
}

// f32 [R][C] -> bf16 [C][R]
__global__ __launch_bounds__(256)
void tcast_k(const float* __restrict__ in, u16* __restrict__ out, int R, int C)
{
  __shared__ float tile[32][33];
  const int tx = threadIdx.x & 31, ty = threadIdx.x >> 5;
  const long long r0 = (long long)blockIdx.y << 5, c0 = (long long)blockIdx.x << 5;
#pragma unroll
  for (int yy = 0; yy < 32; yy += 8)
    tile[ty + yy][tx] = in[(r0 + ty + yy) * C + c0 + tx];
  __syncthreads();
#pragma unroll
  for (int yy = 0; yy < 32; yy += 8)
    out[(c0 + ty + yy) * R + r0 + tx] = f2bf(tile[tx][ty + yy]);
}

__global__ __launch_bounds__(256)
void wqkv_k(const float* __restrict__ Wq, const float* __restrict__ Wk,
            const float* __restrict__ Wv, u16* __restrict__ o)
{
  const int n = blockIdx.y;
  const long long e = (long long)blockIdx.x * 256 + threadIdx.x;
  float v = 0.f;
  if (n < 64)       v = Wq[e * 64 + n];
  else if (n < 128) v = Wk[e * 64 + (n - 64)];
  else if (n < 192) v = Wv[e * 64 + (n - 128)];
  o[(long long)n * 1024 + e] = f2bf(v);
}

__global__ __launch_bounds__(256)
void bqkv_k(const float* __restrict__ bq, const float* __restrict__ bk,
            const float* __restrict__ bv, float* __restrict__ o)
{
  const int n = threadIdx.x;
  float v = 0.f;
  if (n < 64)       v = bq[n];
  else if (n < 128) v = bk[n - 64];
  else if (n < 192) v = bv[n - 128];
  o[n] = v;
}

__global__ __launch_bounds__(256)
void wdsum_k(const float* __restrict__ Wd, u16* __restrict__ o)
{
  const int i = blockIdx.x * 256 + threadIdx.x;
  const int a = i & 63, e = i >> 6;
  float s = 0.f;
#pragma unroll
  for (int hh = 0; hh < 16; ++hh) s += Wd[(long long)(hh * 64 + a) * 1024 + e];
  o[i] = f2bf(s);
}

// qkv = bf16(p0+p1+bqkv) from bf16 partials, plus vT scatter for v-cols
__global__ __launch_bounds__(256)
void reduce_qkv(const u16* __restrict__ p, const float* __restrict__ bqkv,
                u16* __restrict__ qkv, u16* __restrict__ vT)
{
  const long long i4 = (long long)blockIdx.x * 256 + threadIdx.x;
  const int c4 = (int)(i4 & 63);
  const long long row = i4 >> 6;
  u16x4 a = ((const u16x4*)p)[i4];
  u16x4 b2 = ((const u16x4*)p)[i4 + 262144];
  const f32x4 bb = ((const f32x4*)bqkv)[c4];
  u16x4 o;
#pragma unroll
  for (int e = 0; e < 4; ++e) o[e] = f2bf(bf2f(a[e]) + bf2f(b2[e]) + bb[e]);
  ((u16x4*)qkv)[i4] = o;
  if (c4 >= 32 && c4 < 48) {
    const long long b = row >> 11, sidx = row & 2047;
#pragma unroll
    for (int e = 0; e < 4; ++e) {
      const int aa = (c4 - 32) * 4 + e;
      vT[(b * 64 + aa) * 2048 + sidx] = o[e];
    }
  }
}

extern "C" void kernel_launch(void* const* d_in, const int* in_sizes, int n_in,
                              void* d_out, int out_size, void* d_ws, size_t ws_size,
                              hipStream_t stream) {
  const int*   x   = (const int*)d_in[0];
  const float* emb = (const float*)d_in[1];
  const float* Wq  = (const float*)d_in[2];
  const float* bq  = (const float*)d_in[3];
  const float* Wk  = (const float*)d_in[4];
  const float* bk  = (const float*)d_in[5];
  const float* Wv  = (const float*)d_in[6];
  const float* bv  = (const float*)d_in[7];
  const float* Wd  = (const float*)d_in[8];
  const float* bd  = (const float*)d_in[9];
  const float* g1  = (const float*)d_in[10];
  const float* be1 = (const float*)d_in[11];
  const float* g2  = (const float*)d_in[12];
  const float* be2 = (const float*)d_in[13];
  const float* W1  = (const float*)d_in[14];
  const float* c1  = (const float*)d_in[15];
  const float* W2  = (const float*)d_in[16];
  const float* c2  = (const float*)d_in[17];
  const float* Wfc = (const float*)d_in[18];
  const float* bfc = (const float*)d_in[19];
  float* out = (float*)d_out;

  hipFuncSetAttribute(reinterpret_cast<const void*>(gemm8p<0>),
                      hipFuncAttributeMaxDynamicSharedMemorySize, 131072);
  hipFuncSetAttribute(reinterpret_cast<const void*>(gemm8p<2>),
                      hipFuncAttributeMaxDynamicSharedMemorySize, 131072);
  hipFuncSetAttribute(reinterpret_cast<const void*>(gemm8p<3>),
                      hipFuncAttributeMaxDynamicSharedMemorySize, 131072);

  char* ws = (char*)d_ws;
  size_t off = 0;
  auto alloc = [&](size_t bytes) { void* p = ws + off; off = (off + bytes + 255) & ~(size_t)255; return p; };
  float*  h     = (float*) alloc(4096ull * 1024 * 4);
  u16*    z     = (u16*)   alloc(4096ull * 1024 * 2);
  u16*    qkv   = (u16*)   alloc(4096ull * 256 * 2);
  u16*    vT    = (u16*)   alloc(2ull * 64 * 2048 * 2);
  u16*    head  = (u16*)   alloc(4096ull * 64 * 2);
  u16*    mid   = (u16*)   alloc(4096ull * 4096 * 2);
  // SCR aliasing (lifetimes disjoint): partQb [QKV->reduce]; partF [FFN2->reduce_ln]
  char*   SCR   = (char*)  alloc(2ull * 4096 * 1024 * 4);
  u16*    partQb= (u16*)SCR;
  u16*    partF = (u16*)SCR;
  u16*    Wqkvt = (u16*)   alloc(256ull * 1024 * 2);
  float*  bqkv  = (float*) alloc(256 * 4);
  u16*    Wdst  = (u16*)   alloc(1024ull * 64 * 2);
  u16*    W1t   = (u16*)   alloc(4096ull * 1024 * 2);
  u16*    W2t   = (u16*)   alloc(1024ull * 4096 * 2);
  u16*    Wfct  = (u16*)   alloc(32000ull * 1024 * 2);

  // ---- prep (every launch; no caching allowed) ----
  gather_k<<<4096, 256, 0, stream>>>(x, emb, h);
  wqkv_k<<<dim3(4, 256), 256, 0, stream>>>(Wq, Wk, Wv, Wqkvt);
  bqkv_k<<<1, 256, 0, stream>>>(bq, bk, bv, bqkv);
  wdsum_k<<<256, 256, 0, stream>>>(Wd, Wdst);
  tcast_k<<<dim3(128, 32), 256, 0, stream>>>(W1, W1t, 1024, 4096);
  tcast_k<<<dim3(32, 128), 256, 0, stream>>>(W2, W2t, 4096, 1024);
  tcast_k<<<dim3(1000, 32), 256, 0, stream>>>(Wfc, Wfct, 1024, 32000);

  for (int layer = 0; layer < 8; ++layer) {
    if (layer == 0)
      ln_k<<<4096, 256, 0, stream>>>(h, g1, be1, z);
    // partQb[z] = bf16(z1 @ Wqkv^T) (split-K x2, K=512 each) -- legacy engine
    gemm_bt<2><<<dim3(64, 1, 2), 256, 0, stream>>>(z, Wqkvt, nullptr, partQb, nullptr, 1.f,
        512, 1024, 1024, 256, 32, 32, 2, 0, 0, 1048576);
    reduce_qkv<<<1024, 256, 0, stream>>>(partQb, bqkv, qkv, vT);
    // fused attention: 4-wave split-KV, in-LDS LSE merge
    flash4_k<<<256, 256, 0, stream>>>(qkv, vT, head);
    // fused: h += head@Wdsum^T + bd ; z = LN2(h)
    hwd_ln_k<<<256, 256, 0, stream>>>(head, Wdst, bd, h, g2, be2, z);
    // mid = relu(z2 @ W1 + c1) -- R5 engine
    gemm8p<3><<<dim3(256, 1, 1), 512, 131072, stream>>>(z, W1t, nullptr, mid, c1, 1.f,
        1024, 1024, 1024, 4096, 16, 16, 1, 0, 0, 0);
    // partF[sp] = bf16(mid @ W2^T) (split-K x4, K=1024 each) -- R5 engine
    gemm8p<2><<<dim3(64, 1, 4), 512, 131072, stream>>>(mid, W2t, nullptr, partF, nullptr, 1.f,
        1024, 4096, 4096, 1024, 16, 16, 4, 0, 0, 4194304);
    if (layer < 7)
      reduce_ln_k<0><<<4096, 256, 0, stream>>>(partF, h, c2, g1, be1, z);
    else
      reduce_ln_k<1><<<4096, 256, 0, stream>>>(partF, h, c2, nullptr, nullptr, z);
  }
  // out = hb @ Wfc + bfc -- R5 engine, grouped gm=8 (R10-verified best)
  gemm8p<0><<<dim3(2000, 1, 1), 512, 131072, stream>>>(z, Wfct, out, nullptr, bfc, 1.f,
      1024, 1024, 1024, 32000, 16, 8, 1, 0, 0, 0);
}